// Round 9
// baseline (552.521 us; speedup 1.0000x reference)
//
#include <hip/hip_runtime.h>
#include <cstdint>
#include <math.h>

// Problem constants
#define NMC   16
#define SDIM  4
#define ODIM  3
#define TLEN  128
#define BDIM  256
#define MDIM  32
#define HLDIM 64
#define PARD  36

#define LOG2PI_F 1.8378770664093453f

typedef float v2f __attribute__((ext_vector_type(2)));
__device__ __forceinline__ v2f v2(float x, float y) { v2f r; r.x = x; r.y = y; return r; }
__device__ __forceinline__ v2f v2s(float x) { return v2(x, x); }
#define PKFMA(a, b, c) __builtin_elementwise_fma((a), (b), (c))

// ---------------------------------------------------------------------------
// threefry2x32 (JAX-compatible, 20 rounds)
// ---------------------------------------------------------------------------
__host__ __device__ inline void threefry2x32(uint32_t k0, uint32_t k1,
                                             uint32_t x0, uint32_t x1,
                                             uint32_t* o0, uint32_t* o1) {
  uint32_t ks0 = k0, ks1 = k1, ks2 = k0 ^ k1 ^ 0x1BD11BDAu;
  x0 += ks0; x1 += ks1;
#define TF_R(r) { x0 += x1; x1 = (x1 << (r)) | (x1 >> (32 - (r))); x1 ^= x0; }
  TF_R(13) TF_R(15) TF_R(26) TF_R(6)  x0 += ks1; x1 += ks2 + 1u;
  TF_R(17) TF_R(29) TF_R(16) TF_R(24) x0 += ks2; x1 += ks0 + 2u;
  TF_R(13) TF_R(15) TF_R(26) TF_R(6)  x0 += ks0; x1 += ks1 + 3u;
  TF_R(17) TF_R(29) TF_R(16) TF_R(24) x0 += ks1; x1 += ks2 + 4u;
  TF_R(13) TF_R(15) TF_R(26) TF_R(6)  x0 += ks2; x1 += ks0 + 5u;
#undef TF_R
  *o0 = x0; *o1 = x1;
}

// XLA f32 ErfInv polynomial
__device__ inline float erfinv_f32(float x) {
  float w = -log1pf(-x * x);
  float p;
  if (w < 5.0f) {
    w -= 2.5f;
    p = 2.81022636e-08f;
    p = fmaf(p, w, 3.43273939e-07f);
    p = fmaf(p, w, -3.5233877e-06f);
    p = fmaf(p, w, -4.39150654e-06f);
    p = fmaf(p, w, 0.00021858087f);
    p = fmaf(p, w, -0.00125372503f);
    p = fmaf(p, w, -0.00417768164f);
    p = fmaf(p, w, 0.246640727f);
    p = fmaf(p, w, 1.50140941f);
  } else {
    w = sqrtf(w) - 3.0f;
    p = -0.000200214257f;
    p = fmaf(p, w, 0.000100950558f);
    p = fmaf(p, w, 0.00134934322f);
    p = fmaf(p, w, -0.00367342844f);
    p = fmaf(p, w, 0.00573950773f);
    p = fmaf(p, w, -0.0076224613f);
    p = fmaf(p, w, 0.00943887047f);
    p = fmaf(p, w, 1.00167406f);
    p = fmaf(p, w, 2.83297682f);
  }
  return p * x;
}

__device__ inline float bits_to_normal(uint32_t b) {
  float f = __uint_as_float((b >> 9) | 0x3F800000u) - 1.0f;  // [0,1)
  const float lo = -0.99999994f;
  float u = f * 2.0f + lo;
  u = fmaxf(lo, u);
  return 1.41421356f * erfinv_f32(u);
}

// ---------------------------------------------------------------------------
// DPP-based allreduce within each 32-lane group (R7-proven form)
// ---------------------------------------------------------------------------
#define DPP_ROR_ADD(v, ctrl) \
  ((v) + __int_as_float(__builtin_amdgcn_update_dpp(0, __float_as_int(v), (ctrl), 0xf, 0xf, false)))

__device__ __forceinline__ float allred32(float v) {
  v = DPP_ROR_ADD(v, 0x128);  // row_ror:8
  v = DPP_ROR_ADD(v, 0x124);  // row_ror:4
  v = DPP_ROR_ADD(v, 0x122);  // row_ror:2
  v = DPP_ROR_ADD(v, 0x121);  // row_ror:1
  return v + __shfl_xor(v, 16);
}

__device__ __forceinline__ float sigm_fast(float x) {
  return 1.0f / (1.0f + __expf(-x));
}
__device__ __forceinline__ float tanh_fast(float x) {
  return 1.0f - 2.0f / (1.0f + __expf(2.0f * x));
}

// ===========================================================================
// PREP parts (fused kernel; 256 threads; shared smem arena 12480 floats)
// ===========================================================================

// ---- MLP part: blocks [0,512), 64 rows/block -------------------------------
#define MLP_SB 128
__device__ void mlp_part(
    float* smem, const float* __restrict__ obs,
    const float* __restrict__ W1, const float* __restrict__ b1,
    const float* __restrict__ W2, const float* __restrict__ b2,
    const float* __restrict__ W3, const float* __restrict__ b3,
    const float* __restrict__ W4, const float* __restrict__ b4,
    float* __restrict__ par_g) {
  float* xs  = smem;           // [3][64]
  float* A_l = smem + 192;     // 64*64
  float* B_l = smem + 192 + 4096;  // 64*128
  const int tid = threadIdx.x;
  const int R0 = blockIdx.x * 64;
  const int tr = tid & 15;
  const int tj = tid >> 4;

  for (int idx = tid; idx < 192; idx += 256) {
    int r = idx & 63, o = idx >> 6;
    xs[o * 64 + r] = obs[(R0 + r) * 3 + o];
  }

  float acc2[4][8];
#pragma unroll
  for (int i = 0; i < 4; ++i)
#pragma unroll
    for (int j = 0; j < 8; ++j) acc2[i][j] = 0.f;

  for (int kc = 0; kc < 4; ++kc) {
    __syncthreads();
    {  // stage W2 chunk transposed
      int j = tid & 127, kh = (tid >> 7) * 32;
      const float4* wsrc = (const float4*)(W2 + j * 256 + kc * 64 + kh);
#pragma unroll
      for (int q = 0; q < 8; ++q) {
        float4 v = wsrc[q];
        int k = kh + q * 4;
        B_l[(k + 0) * MLP_SB + j] = v.x;
        B_l[(k + 1) * MLP_SB + j] = v.y;
        B_l[(k + 2) * MLP_SB + j] = v.z;
        B_l[(k + 3) * MLP_SB + j] = v.w;
      }
    }
    {  // layer1 on the fly
      int r = tid & 63, q4 = tid >> 6;
      float x0 = xs[r], x1 = xs[64 + r], x2 = xs[128 + r];
      const float4* w1p = (const float4*)(W1 + (kc * 64 + q4 * 16) * 3);
      float4 wv[12];
#pragma unroll
      for (int q = 0; q < 12; ++q) wv[q] = w1p[q];
      const float* wf = (const float*)wv;
#pragma unroll
      for (int i = 0; i < 16; ++i) {
        int k = q4 * 16 + i;
        float v = b1[kc * 64 + k] + wf[i * 3] * x0 + wf[i * 3 + 1] * x1 + wf[i * 3 + 2] * x2;
        A_l[k * 64 + r] = fmaxf(v, 0.f);
      }
    }
    __syncthreads();
    for (int k = 0; k < 64; ++k) {
      float4 av = *(const float4*)&A_l[k * 64 + tr * 4];
      float4 b0 = *(const float4*)&B_l[k * MLP_SB + tj * 8];
      float4 b1v = *(const float4*)&B_l[k * MLP_SB + tj * 8 + 4];
      const float a4[4] = {av.x, av.y, av.z, av.w};
      const float bv8[8] = {b0.x, b0.y, b0.z, b0.w, b1v.x, b1v.y, b1v.z, b1v.w};
#pragma unroll
      for (int ri = 0; ri < 4; ++ri)
#pragma unroll
        for (int ji = 0; ji < 8; ++ji)
          acc2[ri][ji] = fmaf(a4[ri], bv8[ji], acc2[ri][ji]);
    }
  }
  __syncthreads();
#pragma unroll
  for (int ji = 0; ji < 8; ++ji) {
    int j = tj * 8 + ji;
    float bias = b2[j];
    float4 hv;
    hv.x = fmaxf(acc2[0][ji] + bias, 0.f);
    hv.y = fmaxf(acc2[1][ji] + bias, 0.f);
    hv.z = fmaxf(acc2[2][ji] + bias, 0.f);
    hv.w = fmaxf(acc2[3][ji] + bias, 0.f);
    *(float4*)&B_l[j * 64 + tr * 4] = hv;
  }

  float acc3[4][4];
#pragma unroll
  for (int i = 0; i < 4; ++i)
#pragma unroll
    for (int j = 0; j < 4; ++j) acc3[i][j] = 0.f;

  for (int kc = 0; kc < 2; ++kc) {
    __syncthreads();
    {
      int j = tid & 63, kq = (tid >> 6) * 16;
      const float4* wsrc = (const float4*)(W3 + j * 128 + kc * 64 + kq);
#pragma unroll
      for (int q = 0; q < 4; ++q) {
        float4 v = wsrc[q];
        int k = kq + q * 4;
        A_l[(k + 0) * 64 + j] = v.x;
        A_l[(k + 1) * 64 + j] = v.y;
        A_l[(k + 2) * 64 + j] = v.z;
        A_l[(k + 3) * 64 + j] = v.w;
      }
    }
    __syncthreads();
    for (int k = 0; k < 64; ++k) {
      float4 av = *(const float4*)&B_l[(kc * 64 + k) * 64 + tr * 4];
      float4 bv = *(const float4*)&A_l[k * 64 + (tj & 15) * 4];
      const float a4[4] = {av.x, av.y, av.z, av.w};
      const float b4v[4] = {bv.x, bv.y, bv.z, bv.w};
#pragma unroll
      for (int ri = 0; ri < 4; ++ri)
#pragma unroll
        for (int ji = 0; ji < 4; ++ji)
          acc3[ri][ji] = fmaf(a4[ri], b4v[ji], acc3[ri][ji]);
    }
  }
  __syncthreads();
#pragma unroll
  for (int ji = 0; ji < 4; ++ji) {
    int j = tj * 4 + ji;
    float bias = b3[j];
    float4 hv;
    hv.x = fmaxf(acc3[0][ji] + bias, 0.f);
    hv.y = fmaxf(acc3[1][ji] + bias, 0.f);
    hv.z = fmaxf(acc3[2][ji] + bias, 0.f);
    hv.w = fmaxf(acc3[3][ji] + bias, 0.f);
    *(float4*)&A_l[j * 64 + tr * 4] = hv;
  }
  __syncthreads();

  {
    int r = tid & 63;
    int jg = __builtin_amdgcn_readfirstlane(tid >> 6);
    float accp[9];
#pragma unroll
    for (int i = 0; i < 9; ++i) accp[i] = b4[jg * 9 + i];
    for (int k = 0; k < 64; ++k) {
      float hv = A_l[k * 64 + r];
#pragma unroll
      for (int i = 0; i < 9; ++i)
        accp[i] = fmaf(hv, W4[(jg * 9 + i) * 64 + k], accp[i]);
    }
#pragma unroll
    for (int i = 0; i < 9; ++i) par_g[(R0 + r) * 36 + jg * 9 + i] = accp[i];
  }
}

// ---- LSTM part: blocks [512,768) -------------------------------------------
__device__ void lstm_part(
    float* smem, int b, const float* __restrict__ obs,
    const float* __restrict__ Wih, const float* __restrict__ Whh,
    const float* __restrict__ b_lstm,
    const float* __restrict__ Wm, const float* __restrict__ bm,
    const float* __restrict__ Wv, const float* __restrict__ bv,
    float* __restrict__ m0_g, float* __restrict__ v0_g, float* __restrict__ acc) {
  float* g_l = smem;          // [2][4][64]
  float* h_w = smem + 512;    // [4][64]
  float* mv_l = smem + 768;   // 8
  float* obl = smem + 776;    // [128][4] padded
  const int tid = threadIdx.x;
  const int w = tid >> 6;
  const int l = tid & 63;

  for (int i = tid; i < 384; i += 256) obl[(i / 3) * 4 + (i % 3)] = obs[b * 384 + i];

  float whh_r[64];
  {
    const float4* wsrc = (const float4*)(Whh + tid * 64);
#pragma unroll
    for (int q = 0; q < 16; ++q) {
      float4 v = wsrc[q];
      whh_r[q * 4 + 0] = v.x; whh_r[q * 4 + 1] = v.y;
      whh_r[q * 4 + 2] = v.z; whh_r[q * 4 + 3] = v.w;
    }
  }
  const float wih0 = Wih[tid * 3 + 0];
  const float wih1 = Wih[tid * 3 + 1];
  const float wih2 = Wih[tid * 3 + 2];
  const float bb = b_lstm[tid];

  float c_ = 0.0f;
  h_w[w * 64 + l] = 0.0f;
  __syncthreads();

#pragma unroll 1
  for (int t = 0; t < TLEN; ++t) {
    const float4 xv = *(const float4*)&obl[t * 4];
    const float4* h4 = (const float4*)&h_w[w * 64];
    float a0 = 0.f, a1 = 0.f, a2 = 0.f, a3 = 0.f;
#pragma unroll
    for (int q = 0; q < 16; ++q) {
      float4 hv = h4[q];
      a0 = fmaf(whh_r[q * 4 + 0], hv.x, a0);
      a1 = fmaf(whh_r[q * 4 + 1], hv.y, a1);
      a2 = fmaf(whh_r[q * 4 + 2], hv.z, a2);
      a3 = fmaf(whh_r[q * 4 + 3], hv.w, a3);
    }
    float g = fmaf(wih0, xv.x, fmaf(wih1, xv.y, fmaf(wih2, xv.z, bb))) + ((a0 + a1) + (a2 + a3));
    g_l[((t & 1) * 4 + w) * 64 + l] = g;
    __syncthreads();
    float gi = g_l[((t & 1) * 4 + 0) * 64 + l];
    float gf = g_l[((t & 1) * 4 + 1) * 64 + l];
    float gg = g_l[((t & 1) * 4 + 2) * 64 + l];
    float go = g_l[((t & 1) * 4 + 3) * 64 + l];
    c_ = sigm_fast(gf) * c_ + sigm_fast(gi) * tanh_fast(gg);
    h_w[w * 64 + l] = sigm_fast(go) * tanh_fast(c_);
  }

  if (tid < 8) {
    const int s = tid & 3;
    const bool isv = tid >= 4;
    const float* W = isv ? (Wv + s * 64) : (Wm + s * 64);
    float a = isv ? bv[s] : bm[s];
#pragma unroll
    for (int k = 0; k < 64; ++k) a += W[k] * h_w[k];
    if (!isv) {
      m0_g[b * 4 + s] = a;
      mv_l[s] = a;
    } else {
      float sp = (a > 0.f) ? (a + log1pf(expf(-a))) : log1pf(expf(a));
      float v = sp + 1e-6f;
      v0_g[b * 4 + s] = v;
      mv_l[4 + s] = v;
    }
  }
  if (tid == 0) {
    float s = 0.f;
#pragma unroll
    for (int k = 0; k < 4; ++k) {
      float m = mv_l[k], v = mv_l[4 + k];
      s += 0.5f * (v + m * m - 1.0f - logf(v));
    }
    atomicAdd(&acc[0], s);
  }
}

// ---- SETUP part: blocks [768,772), per-d -----------------------------------
// Kinv written PACKED: kinvg[((p*32 + r)*32 + col)*2 + comp], d = 2p+comp.
__device__ void setup_part(
    float* smem, int d, const float* __restrict__ Z,
    const float* __restrict__ log_ls, const float* __restrict__ log_os,
    const float* __restrict__ m_u, const float* __restrict__ L_u,
    uint32_t kUa, uint32_t kUb,
    float* __restrict__ Kinv_g, float* __restrict__ alpha_g, float* __restrict__ acc) {
  float* Kl    = smem;          // 32*33
  float* work  = smem + 1056;   // 32*33
  float* Ul    = smem + 2112;   // 16*32
  float* red   = smem + 2624;   // 64
  float* epsUl = smem + 2688;   // 16*32
  const int tid = threadIdx.x;

  {
    int nn7 = tid >> 5, k = tid & 31;
    uint32_t j = (uint32_t)((nn7 * 4 + d) * 32 + k);
    uint32_t o0, o1;
    threefry2x32(kUa, kUb, j, j + 1024u, &o0, &o1);
    epsUl[nn7 * 32 + k] = bits_to_normal(o0);
    epsUl[(nn7 + 8) * 32 + k] = bits_to_normal(o1);
  }

  float il[4];
#pragma unroll
  for (int k = 0; k < 4; ++k) il[k] = expf(-log_ls[d * 4 + k]);
  const float osd = expf(log_os[d]);

  for (int e = tid; e < 1024; e += 256) {
    int i = e >> 5, j = e & 31;
    float s = 0.f;
#pragma unroll
    for (int k = 0; k < 4; ++k) {
      float t_ = (Z[d * 128 + i * 4 + k] - Z[d * 128 + j * 4 + k]) * il[k];
      s += t_ * t_;
    }
    float v = osd * expf(-0.5f * s);
    if (i == j) v += 1e-5f;
    Kl[i * 33 + j] = v;
  }
  __syncthreads();

  for (int jc = 0; jc < 32; ++jc) {
    if (tid == jc) {
      float s = Kl[jc * 33 + jc];
      for (int p = 0; p < jc; ++p) s -= Kl[jc * 33 + p] * Kl[jc * 33 + p];
      Kl[jc * 33 + jc] = sqrtf(s);
    }
    __syncthreads();
    if (tid > jc && tid < 32) {
      float s = Kl[tid * 33 + jc];
      for (int p = 0; p < jc; ++p) s -= Kl[tid * 33 + p] * Kl[jc * 33 + p];
      Kl[tid * 33 + jc] = s / Kl[jc * 33 + jc];
    }
    __syncthreads();
  }

  if (tid < 32) {
    const int col = tid;
    float rdiag[32];
#pragma unroll
    for (int r = 0; r < 32; ++r) rdiag[r] = __builtin_amdgcn_rcpf(Kl[r * 33 + r]);
    float w[32];
#pragma unroll
    for (int r = 0; r < 32; ++r) {
      float s = (r == col) ? 1.f : 0.f;
#pragma unroll
      for (int p = 0; p < 32; ++p)
        if (p < r) s -= Kl[r * 33 + p] * w[p];
      w[r] = s * rdiag[r];
    }
    float w2[32];
#pragma unroll
    for (int rr = 0; rr < 32; ++rr) {
      const int r = 31 - rr;
      float s = w[r];
#pragma unroll
      for (int p = 0; p < 32; ++p)
        if (p > r) s -= Kl[p * 33 + r] * w2[p];
      w2[r] = s * rdiag[r];
    }
#pragma unroll
    for (int r = 0; r < 32; ++r) {
      Kinv_g[(((d >> 1) * 32 + r) * 32 + col) * 2 + (d & 1)] = w2[r];
      work[col * 33 + r] = w2[r];
    }
  }
  for (int e = tid; e < 512; e += 256) {
    int nn = e >> 5, m = e & 31;
    float s = m_u[d * 32 + m];
    for (int k = 0; k <= m; ++k)
      s += L_u[(d * 32 + m) * 32 + k] * epsUl[nn * 32 + k];
    Ul[nn * 32 + m] = s;
  }
  __syncthreads();
  for (int e = tid; e < 512; e += 256) {
    int nn = e >> 5, m = e & 31;
    float s = 0.f;
    for (int mm = 0; mm < 32; ++mm) s += work[mm * 33 + m] * Ul[nn * 32 + mm];
    alpha_g[(d * 16 + nn) * 32 + m] = s;
  }

  float contrib = 0.f;
  if (tid < 32) {
    const int col = tid;
    float rdiag[32];
#pragma unroll
    for (int r = 0; r < 32; ++r) rdiag[r] = __builtin_amdgcn_rcpf(Kl[r * 33 + r]);
    float v[32];
    float sa = 0.f;
#pragma unroll
    for (int r = 0; r < 32; ++r) {
      float lu = L_u[(d * 32 + r) * 32 + col];
      float s = (col <= r) ? lu : 0.f;
#pragma unroll
      for (int p = 0; p < 32; ++p)
        if (p < r) s -= Kl[r * 33 + p] * v[p];
      float vv = s * rdiag[r];
      v[r] = vv;
      sa += vv * vv;
    }
    contrib = sa;
  } else if (tid < 64) {
    float bq[32];
    float sb = 0.f;
#pragma unroll
    for (int r = 0; r < 32; ++r) {
      float s = m_u[d * 32 + r];
#pragma unroll
      for (int p = 0; p < 32; ++p)
        if (p < r) s -= Kl[r * 33 + p] * bq[p];
      float vv = s * __builtin_amdgcn_rcpf(Kl[r * 33 + r]);
      bq[r] = vv;
      sb += vv * vv;
    }
    contrib = (tid == 32) ? sb : 0.f;
  }
  if (tid < 64) red[tid] = contrib;
  __syncthreads();
  if (tid == 0) {
    float s = 0.f;
    for (int i = 0; i < 64; ++i) s += red[i];
    float ldK = 0.f, ldS = 0.f;
    for (int r = 0; r < 32; ++r) {
      ldK += logf(Kl[r * 33 + r]);
      ldS += logf(fabsf(L_u[(d * 32 + r) * 32 + r]) + 1e-12f);
    }
    float g = s - 32.0f + 2.0f * ldK - 2.0f * ldS;
    atomicAdd(&acc[1], 0.5f * g / (128.0f * 256.0f));
  }
}

// ---- Fused prep kernel (772 blocks) ----------------------------------------
__global__ __launch_bounds__(256) void prep_kernel(
    const float* obs,
    const float* W1, const float* b1, const float* W2, const float* b2,
    const float* W3, const float* b3, const float* W4, const float* b4,
    const float* Wih, const float* Whh, const float* b_lstm,
    const float* Wm, const float* bm, const float* Wv, const float* bv,
    const float* Z, const float* log_ls, const float* log_os,
    const float* m_u, const float* L_u,
    uint32_t kUa, uint32_t kUb,
    float* par_g, float* m0_g, float* v0_g,
    float* Kinv_g, float* alpha_g, float* acc) {
  __shared__ __align__(16) float smem[12480];
  const int bx = blockIdx.x;
  if (bx < 512) {
    mlp_part(smem, obs, W1, b1, W2, b2, W3, b3, W4, b4, par_g);
  } else if (bx < 768) {
    lstm_part(smem, bx - 512, obs, Wih, Whh, b_lstm, Wm, bm, Wv, bv, m0_g, v0_g, acc);
  } else {
    setup_part(smem, bx - 768, Z, log_ls, log_os, m_u, L_u, kUa, kUb,
               Kinv_g, alpha_g, acc);
  }
}

// ===========================================================================
// Scan: 4096 chains; 32 lanes/chain; 2 chains per wave; packed-f32 math
// (R7-proven shfl/DPP cross-lane paths); t=0 RBF peeled out of the loop;
// finalize fused via completion counter.
// ===========================================================================
__global__ __launch_bounds__(256)
__attribute__((amdgpu_waves_per_eu(1, 2)))
void scan_kernel(
    const float* __restrict__ Z, const float* __restrict__ log_ls,
    const float* __restrict__ log_os, const float* __restrict__ noise_proc,
    const float* __restrict__ noise_emis, const float* __restrict__ obs,
    const float* __restrict__ par_g, const float* __restrict__ m0_g,
    const float* __restrict__ v0_g,
    const float* __restrict__ Kinv_g, const float* __restrict__ alpha_g,
    uint32_t k0a, uint32_t k0b, uint32_t kqa, uint32_t kqb,
    float* __restrict__ acc, float* __restrict__ out) {
  __shared__ __align__(16) float parl_raw[32 * 36];
  __shared__ __align__(16) float parl_pk[32 * 40];   // packed per-step records
  __shared__ __align__(16) float obsl[32 * 4];
  __shared__ __align__(16) float eps0l[8 * 4 * 4];
  __shared__ __align__(16) v2f kbufv[8][2][32];      // [chain][dimpair][m]
  __shared__ __align__(16) float epsl[128 * 8 * 4];  // [t][c][s], 16 KB
  const int tid = threadIdx.x;
  const int c = tid >> 5;           // chain in block (0..7); own chain
  const int m = tid & 31;
  const int h = c & 1;              // dim-pair this lane owns (0:{0,1} 1:{2,3})
  const int cp = c & ~1;            // wave's chain pair base
  const int b = blockIdx.x >> 1;
  const int nb = (blockIdx.x & 1) << 3;
  const bool hh = (h != 0);

  // --- prologue RNG ---
#pragma unroll
  for (int i = 0; i < 8; ++i) {
    int e = tid + 256 * i;
    int t = e >> 5, cc = (e >> 2) & 7, ss = e & 3;
    uint32_t j = (uint32_t)(((t * 16 + nb + cc) * 256 + b) * 4 + ss);
    uint32_t o0, o1;
    threefry2x32(kqa, kqb, j, j + 1048576u, &o0, &o1);
    epsl[e] = bits_to_normal(o0);
    epsl[((t + 64) * 8 + cc) * 4 + ss] = bits_to_normal(o1);
  }
  if (tid < 128) {
    int cc = tid >> 4, dd = (tid >> 2) & 3, ss = tid & 3;
    uint32_t j = (uint32_t)((((cc * 4 + dd) * 256 + b) * 4) + ss);
    uint32_t o0, o1;
    threefry2x32(k0a, k0b, j, j + 32768u, &o0, &o1);
    eps0l[(cc * 4 + dd) * 4 + ss] = bits_to_normal(nb ? o1 : o0);
  }

  // --- per-lane constants (dim pair 2h, 2h+1) ---
  v2f ilp[4], nzp[4], osp;
#pragma unroll
  for (int k = 0; k < 4; ++k) {
    float i0 = expf(-log_ls[(2 * h + 0) * 4 + k]);
    float i1 = expf(-log_ls[(2 * h + 1) * 4 + k]);
    ilp[k] = v2(i0, i1);
    nzp[k] = v2(-Z[(2 * h + 0) * 128 + m * 4 + k] * i0,
                -Z[(2 * h + 1) * 128 + m * 4 + k] * i1);
  }
  osp = v2(expf(log_os[2 * h + 0]), expf(log_os[2 * h + 1]));

  v2f kinv2[32];
  {
    const float4* kg4 = (const float4*)Kinv_g;
#pragma unroll
    for (int q = 0; q < 16; ++q) {
      float4 v = kg4[(h * 32 + m) * 16 + q];
      kinv2[2 * q + 0] = v2(v.x, v.y);
      kinv2[2 * q + 1] = v2(v.z, v.w);
    }
  }
  v2f alrp[2];
#pragma unroll
  for (int cc = 0; cc < 2; ++cc)
    alrp[cc] = v2(alpha_g[((2 * h + 0) * 16 + nb + cp + cc) * 32 + m],
                  alpha_g[((2 * h + 1) * 16 + nb + cp + cc) * 32 + m]);
  float np_[4];
#pragma unroll
  for (int k = 0; k < 4; ++k) np_[k] = noise_proc[k];
  const float ine0 = __builtin_amdgcn_rcpf(noise_emis[0]);
  const float ine1 = __builtin_amdgcn_rcpf(noise_emis[1]);
  const float ine2 = __builtin_amdgcn_rcpf(noise_emis[2]);
  const float cst = 3.0f * LOG2PI_F + logf(noise_emis[0]) + logf(noise_emis[1]) + logf(noise_emis[2]);

  const float4 m0v = *(const float4*)(m0_g + b * 4);
  const float4 v0v = *(const float4*)(v0_g + b * 4);
  const float sq0 = sqrtf(v0v.x), sq1 = sqrtf(v0v.y), sq2 = sqrtf(v0v.z), sq3 = sqrtf(v0v.w);

  // --- peeled t=0 RBF (eps0-based; needs cross-wave eps0l -> barrier) ---
  __syncthreads();
  v2f kt0[2];
#pragma unroll
  for (int cc = 0; cc < 2; ++cc) {
    const float4 ea = *(const float4*)&eps0l[((cp + cc) * 4 + 2 * h + 0) * 4];
    const float4 eb = *(const float4*)&eps0l[((cp + cc) * 4 + 2 * h + 1) * 4];
    v2f xt0p = v2(fmaf(sq0, ea.x, m0v.x), fmaf(sq0, eb.x, m0v.x));
    v2f xt1p = v2(fmaf(sq1, ea.y, m0v.y), fmaf(sq1, eb.y, m0v.y));
    v2f xt2p = v2(fmaf(sq2, ea.z, m0v.z), fmaf(sq2, eb.z, m0v.z));
    v2f xt3p = v2(fmaf(sq3, ea.w, m0v.w), fmaf(sq3, eb.w, m0v.w));
    v2f d0 = PKFMA(xt0p, ilp[0], nzp[0]);
    v2f d1 = PKFMA(xt1p, ilp[1], nzp[1]);
    v2f d2 = PKFMA(xt2p, ilp[2], nzp[2]);
    v2f d3 = PKFMA(xt3p, ilp[3], nzp[3]);
    v2f ss = PKFMA(d0, d0, PKFMA(d1, d1, PKFMA(d2, d2, d3 * d3)));
    v2f km = osp * v2(__expf(-0.5f * ss.x), __expf(-0.5f * ss.y));
    kt0[cc] = km;
    kbufv[cp + cc][h][m] = km;
  }

  float x0r = 0.f, x1r = 0.f, x2r = 0.f, x3r = 0.f;  // own chain's x
  float kl_acc = 0.f, ell_acc = 0.f;

  for (int tc = 0; tc < 4; ++tc) {
    __syncthreads();
    {  // stage raw par chunk + obs chunk
      const float4* src = (const float4*)(par_g + (size_t)b * 4608 + tc * 1152);
      float4* dst = (float4*)parl_raw;
      for (int i = tid; i < 288; i += 256) dst[i] = src[i];
      if (tid < 96) obsl[(tid / 3) * 4 + (tid % 3)] = obs[b * 384 + tc * 96 + tid];
    }
    __syncthreads();
    {  // transform to packed layout: 8 workers per step
      int st = tid >> 3, w = tid & 7;
      const float* r = parl_raw + st * 36;
      float* o = parl_pk + st * 40;
      if (w < 4) {              // A column pairs (k = w)
        o[2 * w + 0] = r[0 * 4 + w]; o[2 * w + 1] = r[1 * 4 + w];
        o[8 + 2 * w + 0] = r[2 * 4 + w]; o[8 + 2 * w + 1] = r[3 * 4 + w];
      } else if (w == 4) {      // bt
        o[16] = r[16]; o[17] = r[17]; o[18] = r[18]; o[19] = r[19];
      } else if (w == 5) {      // St col0
        float l00 = r[20];
        o[20] = l00 * l00;
        o[21] = r[24] * l00;
        o[22] = r[28] * l00;
        o[23] = r[32] * l00;
      } else if (w == 6) {      // {St21,St31}, St11
        o[24] = r[28] * r[24] + r[29] * r[25];
        o[25] = r[32] * r[24] + r[33] * r[25];
        o[28] = r[24] * r[24] + r[25] * r[25];
      } else {                  // {St22,St32}, St33
        o[26] = r[28] * r[28] + r[29] * r[29] + r[30] * r[30];
        o[27] = r[32] * r[28] + r[33] * r[29] + r[34] * r[30];
        o[29] = r[32] * r[32] + r[33] * r[33] + r[34] * r[34] + r[35] * r[35];
      }
    }
    __syncthreads();

#pragma unroll 1
    for (int tt = 0; tt < 32; ++tt) {
      const int t = tc * 32 + tt;
      const v2f* pk = (const v2f*)&parl_pk[tt * 40];
      v2f Ac01[4], Ac23[4];
#pragma unroll
      for (int k = 0; k < 4; ++k) { Ac01[k] = pk[k]; Ac23[k] = pk[4 + k]; }
      const v2f bt01 = pk[8], bt23 = pk[9];
      const v2f StA = pk[10];   // {St00,St10}
      const v2f StB = pk[11];   // {St20,St30}
      const v2f StD = pk[12];   // {St21,St31}
      const v2f StE = pk[13];   // {St22,St32}
      const v2f Stx = pk[14];   // {St11,St33}
      const float4 ov = *(const float4*)&obsl[tt * 4];
      const float4 ev = *(const float4*)&epsl[(t * 8 + c) * 4];

      // phase 1: RBF features (dim pair packed) x 2 chains (R7-proven path)
      v2f kregp[2];
      if (t != 0) {
        const float xo0 = __shfl_xor(x0r, 32);
        const float xo1 = __shfl_xor(x1r, 32);
        const float xo2 = __shfl_xor(x2r, 32);
        const float xo3 = __shfl_xor(x3r, 32);
#pragma unroll
        for (int cc = 0; cc < 2; ++cc) {
          const bool own = (cc == h);
          float xt0 = own ? x0r : xo0;
          float xt1 = own ? x1r : xo1;
          float xt2 = own ? x2r : xo2;
          float xt3 = own ? x3r : xo3;
          v2f d0 = PKFMA(v2s(xt0), ilp[0], nzp[0]);
          v2f d1 = PKFMA(v2s(xt1), ilp[1], nzp[1]);
          v2f d2 = PKFMA(v2s(xt2), ilp[2], nzp[2]);
          v2f d3 = PKFMA(v2s(xt3), ilp[3], nzp[3]);
          v2f ss = PKFMA(d0, d0, PKFMA(d1, d1, PKFMA(d2, d2, d3 * d3)));
          v2f km = osp * v2(__expf(-0.5f * ss.x), __expf(-0.5f * ss.y));
          kregp[cc] = km;
          kbufv[cp + cc][h][m] = km;   // wave-internal write
        }
      } else {
        kregp[0] = kt0[0];
        kregp[1] = kt0[1];             // kbuf already holds t0 values
      }

      // phase 2: matvec (packed) + reductions, both chains
      v2f gmloc[2], gvloc[2];
#pragma unroll
      for (int cc = 0; cc < 2; ++cc) {
        const float4* kb4 = (const float4*)&kbufv[cp + cc][h][0];
        v2f aA = v2s(0.f), aB = v2s(0.f);
#pragma unroll
        for (int q = 0; q < 16; ++q) {
          float4 kv = kb4[q];
          aA = PKFMA(kinv2[2 * q + 0], v2(kv.x, kv.y), aA);
          aB = PKFMA(kinv2[2 * q + 1], v2(kv.z, kv.w), aB);
        }
        v2f yp = aA + aB;
        v2f gmp = kregp[cc] * alrp[cc];
        v2f qpp = kregp[cc] * yp;
        gmloc[cc] = v2(allred32(gmp.x), allred32(gmp.y));
        v2f qpr = v2(allred32(qpp.x), allred32(qpp.y));
        gvloc[cc] = __builtin_elementwise_max(osp - qpr, v2s(1e-8f));
      }

      // cross-half exchange (R7-proven): send the OTHER chain's values;
      // receive the partner half's values for OUR chain's other dim-pair.
      v2f sgm = hh ? gmloc[0] : gmloc[1];
      v2f sgv = hh ? gvloc[0] : gvloc[1];
      v2f rgm = v2(__shfl_xor(sgm.x, 32), __shfl_xor(sgm.y, 32));
      v2f rgv = v2(__shfl_xor(sgv.x, 32), __shfl_xor(sgv.y, 32));
      v2f lgm = hh ? gmloc[1] : gmloc[0];
      v2f lgv = hh ? gvloc[1] : gvloc[0];
      v2f gm01 = hh ? rgm : lgm;
      v2f gm23 = hh ? lgm : rgm;
      v2f gv01 = hh ? rgv : lgv;
      v2f gv23 = hh ? lgv : rgv;
      const float gm0 = gm01.x, gm1 = gm01.y, gm2 = gm23.x, gm3 = gm23.y;
      const float gv0 = gv01.x, gv1 = gv01.y, gv2 = gv23.x, gv3 = gv23.y;

      // q_mean (row pairs)
      v2f qm01 = bt01, qm23 = bt23;
      qm01 = PKFMA(Ac01[0], v2s(gm0), qm01);
      qm01 = PKFMA(Ac01[1], v2s(gm1), qm01);
      qm01 = PKFMA(Ac01[2], v2s(gm2), qm01);
      qm01 = PKFMA(Ac01[3], v2s(gm3), qm01);
      qm23 = PKFMA(Ac23[0], v2s(gm0), qm23);
      qm23 = PKFMA(Ac23[1], v2s(gm1), qm23);
      qm23 = PKFMA(Ac23[2], v2s(gm2), qm23);
      qm23 = PKFMA(Ac23[3], v2s(gm3), qm23);

      // B = A * diag(gv), row pairs
      v2f B01[4], B23[4];
      B01[0] = Ac01[0] * v2s(gv0); B23[0] = Ac23[0] * v2s(gv0);
      B01[1] = Ac01[1] * v2s(gv1); B23[1] = Ac23[1] * v2s(gv1);
      B01[2] = Ac01[2] * v2s(gv2); B23[2] = Ac23[2] * v2s(gv2);
      B01[3] = Ac01[3] * v2s(gv3); B23[3] = Ac23[3] * v2s(gv3);

      // q_cov = St + B A^T (lower triangle, packed)
      v2f c0a = StA, c0b = StB, c1 = StD, c2 = StE;
      float c11 = Stx.x, c33 = Stx.y;
#pragma unroll
      for (int k = 0; k < 4; ++k) {
        float A0k = Ac01[k].x, A1k = Ac01[k].y, A2k = Ac23[k].x, A3k = Ac23[k].y;
        c0a = PKFMA(B01[k], v2s(A0k), c0a);   // {qc00, qc10}
        c0b = PKFMA(B23[k], v2s(A0k), c0b);   // {qc20, qc30}
        c1  = PKFMA(B23[k], v2s(A1k), c1);    // {qc21, qc31}
        c2  = PKFMA(B23[k], v2s(A2k), c2);    // {qc22, qc32}
        c11 = fmaf(B01[k].y, A1k, c11);
        c33 = fmaf(B23[k].y, A3k, c33);
      }
      const float qc00 = c0a.x, qc10 = c0a.y, qc20 = c0b.x, qc30 = c0b.y;
      const float qc11 = c11, qc21 = c1.x, qc31 = c1.y;
      const float qc22 = c2.x, qc32 = c2.y, qc33 = c33;

      // Cholesky via rsq
      float t00 = qc00 + 1e-6f;
      float i0 = __builtin_amdgcn_rsqf(t00);
      float l00 = t00 * i0;
      float l10 = qc10 * i0, l20 = qc20 * i0, l30 = qc30 * i0;
      float t11 = qc11 + 1e-6f - l10 * l10;
      float i1 = __builtin_amdgcn_rsqf(t11);
      float l11 = t11 * i1;
      float l21 = (qc21 - l20 * l10) * i1;
      float l31 = (qc31 - l30 * l10) * i1;
      float t22 = qc22 + 1e-6f - l20 * l20 - l21 * l21;
      float i2 = __builtin_amdgcn_rsqf(t22);
      float l22 = t22 * i2;
      float l32 = (qc32 - l30 * l20 - l31 * l21) * i2;
      float t33 = qc33 + 1e-6f - l30 * l30 - l31 * l31 - l32 * l32;
      float l33 = t33 * __builtin_amdgcn_rsqf(t33);
      float logdet_q = __logf(t00 * t11 * t22 * t33);

      float dp0 = gv0 + np_[0], dp1 = gv1 + np_[1];
      float dp2 = gv2 + np_[2], dp3 = gv3 + np_[3];
      float rp0 = __builtin_amdgcn_rcpf(dp0), rp1 = __builtin_amdgcn_rcpf(dp1);
      float rp2 = __builtin_amdgcn_rcpf(dp2), rp3 = __builtin_amdgcn_rcpf(dp3);
      v2f e01 = gm01 - qm01, e23 = gm23 - qm23;
      float klsum = (qc00 + e01.x * e01.x) * rp0 + (qc11 + e01.y * e01.y) * rp1 +
                    (qc22 + e23.x * e23.x) * rp2 + (qc33 + e23.y * e23.y) * rp3;
      float kl = 0.5f * (klsum - 4.0f + __logf(dp0 * dp1 * dp2 * dp3) - logdet_q);
      kl_acc += kl;

      float dy0 = ov.x - qm01.x, dy1 = ov.y - qm01.y, dy2 = ov.z - qm23.x;
      float es = -0.5f * (cst + (dy0 * dy0 + qc00) * ine0 +
                          (dy1 * dy1 + qc11) * ine1 + (dy2 * dy2 + qc22) * ine2);
      ell_acc += es;

      x0r = qm01.x + l00 * ev.x;
      x1r = qm01.y + l10 * ev.x + l11 * ev.y;
      x2r = qm23.x + l20 * ev.x + l21 * ev.y + l22 * ev.z;
      x3r = qm23.y + l30 * ev.x + l31 * ev.y + l32 * ev.z + l33 * ev.w;
    }
  }

  if (m == 0) {
    atomicAdd(&acc[2], kl_acc);
    atomicAdd(&acc[3], ell_acc);
  }
  __syncthreads();
  // fused finalize: last block to finish computes the ELBO
  if (tid == 0) {
    __threadfence();
    unsigned prev = atomicAdd((unsigned int*)&acc[8], 1u);
    if (prev == 511u) {
      __threadfence();
      float qm0 = atomicAdd(&acc[0], 0.0f) / 256.0f;
      float gpKL = atomicAdd(&acc[1], 0.0f);
      float KL = atomicAdd(&acc[2], 0.0f) / 4096.0f;
      float lik = atomicAdd(&acc[3], 0.0f) / 4096.0f;
      float e = -qm0 - gpKL + lik - KL;
      if (lik > KL) e = -qm0 - gpKL + lik / 128.0f - KL;
      out[0] = e;
    }
  }
}

// ---------------------------------------------------------------------------
extern "C" void kernel_launch(void* const* d_in, const int* in_sizes, int n_in,
                              void* d_out, int out_size, void* d_ws, size_t ws_size,
                              hipStream_t stream) {
  const float* obs        = (const float*)d_in[0];
  const float* Z          = (const float*)d_in[1];
  const float* log_ls     = (const float*)d_in[2];
  const float* log_os     = (const float*)d_in[3];
  const float* m_u        = (const float*)d_in[4];
  const float* L_u        = (const float*)d_in[5];
  const float* noise_proc = (const float*)d_in[6];
  const float* noise_emis = (const float*)d_in[7];
  const float* Wih        = (const float*)d_in[8];
  const float* Whh        = (const float*)d_in[9];
  const float* b_lstm     = (const float*)d_in[10];
  const float* Wm         = (const float*)d_in[11];
  const float* bm         = (const float*)d_in[12];
  const float* Wv         = (const float*)d_in[13];
  const float* bv         = (const float*)d_in[14];
  const float* W1         = (const float*)d_in[15];
  const float* b1         = (const float*)d_in[16];
  const float* W2         = (const float*)d_in[17];
  const float* b2         = (const float*)d_in[18];
  const float* W3         = (const float*)d_in[19];
  const float* b3         = (const float*)d_in[20];
  const float* W4         = (const float*)d_in[21];
  const float* b4         = (const float*)d_in[22];

  float* ws = (float*)d_ws;
  float* m0_g  = ws;                 // 1024
  float* v0_g  = m0_g + 1024;        // 1024
  float* par_g = v0_g + 1024;        // 1179648
  float* kinvg = par_g + 1179648;    // 4096 (packed v2f layout)
  float* alphg = kinvg + 4096;       // 2048
  float* accp  = alphg + 2048;       // 16 (acc[8] doubles as completion cnt)

  hipMemsetAsync(accp, 0, 64, stream);

  // JAX: rng = key(42) -> (0,42); k0,kU,kq = split(rng,3)
  uint32_t A0, B0, A1, B1, A2, B2;
  threefry2x32(0u, 42u, 0u, 3u, &A0, &B0);
  threefry2x32(0u, 42u, 1u, 4u, &A1, &B1);
  threefry2x32(0u, 42u, 2u, 5u, &A2, &B2);
  const uint32_t k0a = A0, k0b = A1;   // k0
  const uint32_t kUa = A2, kUb = B0;   // kU
  const uint32_t kqa = B1, kqb = B2;   // kq

  // prep: mlp [0,512) + lstm [512,768) + setup [768,772)
  prep_kernel<<<772, 256, 0, stream>>>(
      obs, W1, b1, W2, b2, W3, b3, W4, b4,
      Wih, Whh, b_lstm, Wm, bm, Wv, bv,
      Z, log_ls, log_os, m_u, L_u,
      kUa, kUb,
      par_g, m0_g, v0_g, kinvg, alphg, accp);

  scan_kernel<<<512, 256, 0, stream>>>(
      Z, log_ls, log_os, noise_proc, noise_emis, obs,
      par_g, m0_g, v0_g, kinvg, alphg, k0a, k0b, kqa, kqb, accp,
      (float*)d_out);
}

// Round 10
// 535.210 us; speedup vs baseline: 1.0323x; 1.0323x over previous
//
#include <hip/hip_runtime.h>
#include <cstdint>
#include <math.h>

// Problem constants
#define NMC   16
#define SDIM  4
#define ODIM  3
#define TLEN  128
#define BDIM  256
#define MDIM  32
#define HLDIM 64
#define PARD  36

#define LOG2PI_F 1.8378770664093453f

typedef float v2f __attribute__((ext_vector_type(2)));
__device__ __forceinline__ v2f v2(float x, float y) { v2f r; r.x = x; r.y = y; return r; }
__device__ __forceinline__ v2f v2s(float x) { return v2(x, x); }
#define PKFMA(a, b, c) __builtin_elementwise_fma((a), (b), (c))

// ---------------------------------------------------------------------------
// threefry2x32 (JAX-compatible, 20 rounds)
// ---------------------------------------------------------------------------
__host__ __device__ inline void threefry2x32(uint32_t k0, uint32_t k1,
                                             uint32_t x0, uint32_t x1,
                                             uint32_t* o0, uint32_t* o1) {
  uint32_t ks0 = k0, ks1 = k1, ks2 = k0 ^ k1 ^ 0x1BD11BDAu;
  x0 += ks0; x1 += ks1;
#define TF_R(r) { x0 += x1; x1 = (x1 << (r)) | (x1 >> (32 - (r))); x1 ^= x0; }
  TF_R(13) TF_R(15) TF_R(26) TF_R(6)  x0 += ks1; x1 += ks2 + 1u;
  TF_R(17) TF_R(29) TF_R(16) TF_R(24) x0 += ks2; x1 += ks0 + 2u;
  TF_R(13) TF_R(15) TF_R(26) TF_R(6)  x0 += ks0; x1 += ks1 + 3u;
  TF_R(17) TF_R(29) TF_R(16) TF_R(24) x0 += ks1; x1 += ks2 + 4u;
  TF_R(13) TF_R(15) TF_R(26) TF_R(6)  x0 += ks2; x1 += ks0 + 5u;
#undef TF_R
  *o0 = x0; *o1 = x1;
}

// XLA f32 ErfInv polynomial
__device__ inline float erfinv_f32(float x) {
  float w = -log1pf(-x * x);
  float p;
  if (w < 5.0f) {
    w -= 2.5f;
    p = 2.81022636e-08f;
    p = fmaf(p, w, 3.43273939e-07f);
    p = fmaf(p, w, -3.5233877e-06f);
    p = fmaf(p, w, -4.39150654e-06f);
    p = fmaf(p, w, 0.00021858087f);
    p = fmaf(p, w, -0.00125372503f);
    p = fmaf(p, w, -0.00417768164f);
    p = fmaf(p, w, 0.246640727f);
    p = fmaf(p, w, 1.50140941f);
  } else {
    w = sqrtf(w) - 3.0f;
    p = -0.000200214257f;
    p = fmaf(p, w, 0.000100950558f);
    p = fmaf(p, w, 0.00134934322f);
    p = fmaf(p, w, -0.00367342844f);
    p = fmaf(p, w, 0.00573950773f);
    p = fmaf(p, w, -0.0076224613f);
    p = fmaf(p, w, 0.00943887047f);
    p = fmaf(p, w, 1.00167406f);
    p = fmaf(p, w, 2.83297682f);
  }
  return p * x;
}

__device__ inline float bits_to_normal(uint32_t b) {
  float f = __uint_as_float((b >> 9) | 0x3F800000u) - 1.0f;  // [0,1)
  const float lo = -0.99999994f;
  float u = f * 2.0f + lo;
  u = fmaxf(lo, u);
  return 1.41421356f * erfinv_f32(u);
}

// ---------------------------------------------------------------------------
// DPP-based allreduce within each 32-lane group (R7-proven form)
// ---------------------------------------------------------------------------
#define DPP_ROR_ADD(v, ctrl) \
  ((v) + __int_as_float(__builtin_amdgcn_update_dpp(0, __float_as_int(v), (ctrl), 0xf, 0xf, false)))

__device__ __forceinline__ float allred32(float v) {
  v = DPP_ROR_ADD(v, 0x128);  // row_ror:8
  v = DPP_ROR_ADD(v, 0x124);  // row_ror:4
  v = DPP_ROR_ADD(v, 0x122);  // row_ror:2
  v = DPP_ROR_ADD(v, 0x121);  // row_ror:1
  return v + __shfl_xor(v, 16);
}

__device__ __forceinline__ float sigm_fast(float x) {
  return 1.0f / (1.0f + __expf(-x));
}
__device__ __forceinline__ float tanh_fast(float x) {
  return 1.0f - 2.0f / (1.0f + __expf(2.0f * x));
}

// ===========================================================================
// PREP parts (fused kernel; 256 threads; shared smem arena 12480 floats)
// ===========================================================================

// ---- MLP part: blocks [0,512), 64 rows/block -------------------------------
#define MLP_SB 128
__device__ void mlp_part(
    float* smem, const float* __restrict__ obs,
    const float* __restrict__ W1, const float* __restrict__ b1,
    const float* __restrict__ W2, const float* __restrict__ b2,
    const float* __restrict__ W3, const float* __restrict__ b3,
    const float* __restrict__ W4, const float* __restrict__ b4,
    float* __restrict__ par_g) {
  float* xs  = smem;           // [3][64]
  float* A_l = smem + 192;     // 64*64
  float* B_l = smem + 192 + 4096;  // 64*128
  const int tid = threadIdx.x;
  const int R0 = blockIdx.x * 64;
  const int tr = tid & 15;
  const int tj = tid >> 4;

  for (int idx = tid; idx < 192; idx += 256) {
    int r = idx & 63, o = idx >> 6;
    xs[o * 64 + r] = obs[(R0 + r) * 3 + o];
  }

  float acc2[4][8];
#pragma unroll
  for (int i = 0; i < 4; ++i)
#pragma unroll
    for (int j = 0; j < 8; ++j) acc2[i][j] = 0.f;

  for (int kc = 0; kc < 4; ++kc) {
    __syncthreads();
    {  // stage W2 chunk transposed
      int j = tid & 127, kh = (tid >> 7) * 32;
      const float4* wsrc = (const float4*)(W2 + j * 256 + kc * 64 + kh);
#pragma unroll
      for (int q = 0; q < 8; ++q) {
        float4 v = wsrc[q];
        int k = kh + q * 4;
        B_l[(k + 0) * MLP_SB + j] = v.x;
        B_l[(k + 1) * MLP_SB + j] = v.y;
        B_l[(k + 2) * MLP_SB + j] = v.z;
        B_l[(k + 3) * MLP_SB + j] = v.w;
      }
    }
    {  // layer1 on the fly
      int r = tid & 63, q4 = tid >> 6;
      float x0 = xs[r], x1 = xs[64 + r], x2 = xs[128 + r];
      const float4* w1p = (const float4*)(W1 + (kc * 64 + q4 * 16) * 3);
      float4 wv[12];
#pragma unroll
      for (int q = 0; q < 12; ++q) wv[q] = w1p[q];
      const float* wf = (const float*)wv;
#pragma unroll
      for (int i = 0; i < 16; ++i) {
        int k = q4 * 16 + i;
        float v = b1[kc * 64 + k] + wf[i * 3] * x0 + wf[i * 3 + 1] * x1 + wf[i * 3 + 2] * x2;
        A_l[k * 64 + r] = fmaxf(v, 0.f);
      }
    }
    __syncthreads();
    for (int k = 0; k < 64; ++k) {
      float4 av = *(const float4*)&A_l[k * 64 + tr * 4];
      float4 b0 = *(const float4*)&B_l[k * MLP_SB + tj * 8];
      float4 b1v = *(const float4*)&B_l[k * MLP_SB + tj * 8 + 4];
      const float a4[4] = {av.x, av.y, av.z, av.w};
      const float bv8[8] = {b0.x, b0.y, b0.z, b0.w, b1v.x, b1v.y, b1v.z, b1v.w};
#pragma unroll
      for (int ri = 0; ri < 4; ++ri)
#pragma unroll
        for (int ji = 0; ji < 8; ++ji)
          acc2[ri][ji] = fmaf(a4[ri], bv8[ji], acc2[ri][ji]);
    }
  }
  __syncthreads();
#pragma unroll
  for (int ji = 0; ji < 8; ++ji) {
    int j = tj * 8 + ji;
    float bias = b2[j];
    float4 hv;
    hv.x = fmaxf(acc2[0][ji] + bias, 0.f);
    hv.y = fmaxf(acc2[1][ji] + bias, 0.f);
    hv.z = fmaxf(acc2[2][ji] + bias, 0.f);
    hv.w = fmaxf(acc2[3][ji] + bias, 0.f);
    *(float4*)&B_l[j * 64 + tr * 4] = hv;
  }

  float acc3[4][4];
#pragma unroll
  for (int i = 0; i < 4; ++i)
#pragma unroll
    for (int j = 0; j < 4; ++j) acc3[i][j] = 0.f;

  for (int kc = 0; kc < 2; ++kc) {
    __syncthreads();
    {
      int j = tid & 63, kq = (tid >> 6) * 16;
      const float4* wsrc = (const float4*)(W3 + j * 128 + kc * 64 + kq);
#pragma unroll
      for (int q = 0; q < 4; ++q) {
        float4 v = wsrc[q];
        int k = kq + q * 4;
        A_l[(k + 0) * 64 + j] = v.x;
        A_l[(k + 1) * 64 + j] = v.y;
        A_l[(k + 2) * 64 + j] = v.z;
        A_l[(k + 3) * 64 + j] = v.w;
      }
    }
    __syncthreads();
    for (int k = 0; k < 64; ++k) {
      float4 av = *(const float4*)&B_l[(kc * 64 + k) * 64 + tr * 4];
      float4 bv = *(const float4*)&A_l[k * 64 + (tj & 15) * 4];
      const float a4[4] = {av.x, av.y, av.z, av.w};
      const float b4v[4] = {bv.x, bv.y, bv.z, bv.w};
#pragma unroll
      for (int ri = 0; ri < 4; ++ri)
#pragma unroll
        for (int ji = 0; ji < 4; ++ji)
          acc3[ri][ji] = fmaf(a4[ri], b4v[ji], acc3[ri][ji]);
    }
  }
  __syncthreads();
#pragma unroll
  for (int ji = 0; ji < 4; ++ji) {
    int j = tj * 4 + ji;
    float bias = b3[j];
    float4 hv;
    hv.x = fmaxf(acc3[0][ji] + bias, 0.f);
    hv.y = fmaxf(acc3[1][ji] + bias, 0.f);
    hv.z = fmaxf(acc3[2][ji] + bias, 0.f);
    hv.w = fmaxf(acc3[3][ji] + bias, 0.f);
    *(float4*)&A_l[j * 64 + tr * 4] = hv;
  }
  __syncthreads();

  {
    int r = tid & 63;
    int jg = __builtin_amdgcn_readfirstlane(tid >> 6);
    float accp[9];
#pragma unroll
    for (int i = 0; i < 9; ++i) accp[i] = b4[jg * 9 + i];
    for (int k = 0; k < 64; ++k) {
      float hv = A_l[k * 64 + r];
#pragma unroll
      for (int i = 0; i < 9; ++i)
        accp[i] = fmaf(hv, W4[(jg * 9 + i) * 64 + k], accp[i]);
    }
#pragma unroll
    for (int i = 0; i < 9; ++i) par_g[(R0 + r) * 36 + jg * 9 + i] = accp[i];
  }
}

// ---- LSTM part: blocks [512,768) -------------------------------------------
__device__ void lstm_part(
    float* smem, int b, const float* __restrict__ obs,
    const float* __restrict__ Wih, const float* __restrict__ Whh,
    const float* __restrict__ b_lstm,
    const float* __restrict__ Wm, const float* __restrict__ bm,
    const float* __restrict__ Wv, const float* __restrict__ bv,
    float* __restrict__ m0_g, float* __restrict__ v0_g, float* __restrict__ acc) {
  float* g_l = smem;          // [2][4][64]
  float* h_w = smem + 512;    // [4][64]
  float* mv_l = smem + 768;   // 8
  float* obl = smem + 776;    // [128][4] padded
  const int tid = threadIdx.x;
  const int w = tid >> 6;
  const int l = tid & 63;

  for (int i = tid; i < 384; i += 256) obl[(i / 3) * 4 + (i % 3)] = obs[b * 384 + i];

  float whh_r[64];
  {
    const float4* wsrc = (const float4*)(Whh + tid * 64);
#pragma unroll
    for (int q = 0; q < 16; ++q) {
      float4 v = wsrc[q];
      whh_r[q * 4 + 0] = v.x; whh_r[q * 4 + 1] = v.y;
      whh_r[q * 4 + 2] = v.z; whh_r[q * 4 + 3] = v.w;
    }
  }
  const float wih0 = Wih[tid * 3 + 0];
  const float wih1 = Wih[tid * 3 + 1];
  const float wih2 = Wih[tid * 3 + 2];
  const float bb = b_lstm[tid];

  float c_ = 0.0f;
  h_w[w * 64 + l] = 0.0f;
  __syncthreads();

#pragma unroll 1
  for (int t = 0; t < TLEN; ++t) {
    const float4 xv = *(const float4*)&obl[t * 4];
    const float4* h4 = (const float4*)&h_w[w * 64];
    float a0 = 0.f, a1 = 0.f, a2 = 0.f, a3 = 0.f;
#pragma unroll
    for (int q = 0; q < 16; ++q) {
      float4 hv = h4[q];
      a0 = fmaf(whh_r[q * 4 + 0], hv.x, a0);
      a1 = fmaf(whh_r[q * 4 + 1], hv.y, a1);
      a2 = fmaf(whh_r[q * 4 + 2], hv.z, a2);
      a3 = fmaf(whh_r[q * 4 + 3], hv.w, a3);
    }
    float g = fmaf(wih0, xv.x, fmaf(wih1, xv.y, fmaf(wih2, xv.z, bb))) + ((a0 + a1) + (a2 + a3));
    g_l[((t & 1) * 4 + w) * 64 + l] = g;
    __syncthreads();
    float gi = g_l[((t & 1) * 4 + 0) * 64 + l];
    float gf = g_l[((t & 1) * 4 + 1) * 64 + l];
    float gg = g_l[((t & 1) * 4 + 2) * 64 + l];
    float go = g_l[((t & 1) * 4 + 3) * 64 + l];
    c_ = sigm_fast(gf) * c_ + sigm_fast(gi) * tanh_fast(gg);
    h_w[w * 64 + l] = sigm_fast(go) * tanh_fast(c_);
  }

  if (tid < 8) {
    const int s = tid & 3;
    const bool isv = tid >= 4;
    const float* W = isv ? (Wv + s * 64) : (Wm + s * 64);
    float a = isv ? bv[s] : bm[s];
#pragma unroll
    for (int k = 0; k < 64; ++k) a += W[k] * h_w[k];
    if (!isv) {
      m0_g[b * 4 + s] = a;
      mv_l[s] = a;
    } else {
      float sp = (a > 0.f) ? (a + log1pf(expf(-a))) : log1pf(expf(a));
      float v = sp + 1e-6f;
      v0_g[b * 4 + s] = v;
      mv_l[4 + s] = v;
    }
  }
  if (tid == 0) {
    float s = 0.f;
#pragma unroll
    for (int k = 0; k < 4; ++k) {
      float m = mv_l[k], v = mv_l[4 + k];
      s += 0.5f * (v + m * m - 1.0f - logf(v));
    }
    atomicAdd(&acc[0], s);
  }
}

// ---- SETUP part: blocks [768,772), per-d -----------------------------------
// Writes ROTATED pre-scaled symmetric-fold kernel matrix:
//   Krot_g[(p*32+m)*34 + j*2 + comp], d = 2p+comp, j in [0,17):
//     j==0 : Kinv[m][m];  j in 1..15 : 2*Kinv[m][(m+j)&31];  j==16 : Kinv[m][(m+16)&31]
__device__ void setup_part(
    float* smem, int d, const float* __restrict__ Z,
    const float* __restrict__ log_ls, const float* __restrict__ log_os,
    const float* __restrict__ m_u, const float* __restrict__ L_u,
    uint32_t kUa, uint32_t kUb,
    float* __restrict__ Krot_g, float* __restrict__ alpha_g, float* __restrict__ acc) {
  float* Kl    = smem;          // 32*33
  float* work  = smem + 1056;   // 32*33
  float* Ul    = smem + 2112;   // 16*32
  float* red   = smem + 2624;   // 64
  float* epsUl = smem + 2688;   // 16*32
  const int tid = threadIdx.x;

  {
    int nn7 = tid >> 5, k = tid & 31;
    uint32_t j = (uint32_t)((nn7 * 4 + d) * 32 + k);
    uint32_t o0, o1;
    threefry2x32(kUa, kUb, j, j + 1024u, &o0, &o1);
    epsUl[nn7 * 32 + k] = bits_to_normal(o0);
    epsUl[(nn7 + 8) * 32 + k] = bits_to_normal(o1);
  }

  float il[4];
#pragma unroll
  for (int k = 0; k < 4; ++k) il[k] = expf(-log_ls[d * 4 + k]);
  const float osd = expf(log_os[d]);

  for (int e = tid; e < 1024; e += 256) {
    int i = e >> 5, j = e & 31;
    float s = 0.f;
#pragma unroll
    for (int k = 0; k < 4; ++k) {
      float t_ = (Z[d * 128 + i * 4 + k] - Z[d * 128 + j * 4 + k]) * il[k];
      s += t_ * t_;
    }
    float v = osd * expf(-0.5f * s);
    if (i == j) v += 1e-5f;
    Kl[i * 33 + j] = v;
  }
  __syncthreads();

  for (int jc = 0; jc < 32; ++jc) {
    if (tid == jc) {
      float s = Kl[jc * 33 + jc];
      for (int p = 0; p < jc; ++p) s -= Kl[jc * 33 + p] * Kl[jc * 33 + p];
      Kl[jc * 33 + jc] = sqrtf(s);
    }
    __syncthreads();
    if (tid > jc && tid < 32) {
      float s = Kl[tid * 33 + jc];
      for (int p = 0; p < jc; ++p) s -= Kl[tid * 33 + p] * Kl[jc * 33 + p];
      Kl[tid * 33 + jc] = s / Kl[jc * 33 + jc];
    }
    __syncthreads();
  }

  if (tid < 32) {
    const int col = tid;
    float rdiag[32];
#pragma unroll
    for (int r = 0; r < 32; ++r) rdiag[r] = __builtin_amdgcn_rcpf(Kl[r * 33 + r]);
    float w[32];
#pragma unroll
    for (int r = 0; r < 32; ++r) {
      float s = (r == col) ? 1.f : 0.f;
#pragma unroll
      for (int p = 0; p < 32; ++p)
        if (p < r) s -= Kl[r * 33 + p] * w[p];
      w[r] = s * rdiag[r];
    }
    float w2[32];
#pragma unroll
    for (int rr = 0; rr < 32; ++rr) {
      const int r = 31 - rr;
      float s = w[r];
#pragma unroll
      for (int p = 0; p < 32; ++p)
        if (p > r) s -= Kl[p * 33 + r] * w2[p];
      w2[r] = s * rdiag[r];
    }
#pragma unroll
    for (int r = 0; r < 32; ++r) work[col * 33 + r] = w2[r];
  }
  for (int e = tid; e < 512; e += 256) {
    int nn = e >> 5, m = e & 31;
    float s = m_u[d * 32 + m];
    for (int k = 0; k <= m; ++k)
      s += L_u[(d * 32 + m) * 32 + k] * epsUl[nn * 32 + k];
    Ul[nn * 32 + m] = s;
  }
  __syncthreads();
  for (int e = tid; e < 512; e += 256) {
    int nn = e >> 5, m = e & 31;
    float s = 0.f;
    for (int mm = 0; mm < 32; ++mm) s += work[mm * 33 + m] * Ul[nn * 32 + mm];
    alpha_g[(d * 16 + nn) * 32 + m] = s;
  }
  __syncthreads();  // work reads (alpha) done before krot extraction below

  // Rotated pre-scaled Krot for the symmetric quadratic-form fold.
  // Kinv[m][col] = work[col*33 + m] (Kinv symmetric).
  for (int e = tid; e < 32 * 17; e += 256) {
    int mm = e / 17, j = e - mm * 17;
    int col = (mm + j) & 31;
    float scale = (j == 0 || j == 16) ? 1.0f : 2.0f;
    Krot_g[((d >> 1) * 32 + mm) * 34 + j * 2 + (d & 1)] = scale * work[col * 33 + mm];
  }
  __syncthreads();  // krot reads done before gpKL overwrites work

  float contrib = 0.f;
  if (tid < 32) {
    const int col = tid;
    float rdiag[32];
#pragma unroll
    for (int r = 0; r < 32; ++r) rdiag[r] = __builtin_amdgcn_rcpf(Kl[r * 33 + r]);
    float v[32];
    float sa = 0.f;
#pragma unroll
    for (int r = 0; r < 32; ++r) {
      float lu = L_u[(d * 32 + r) * 32 + col];
      float s = (col <= r) ? lu : 0.f;
#pragma unroll
      for (int p = 0; p < 32; ++p)
        if (p < r) s -= Kl[r * 33 + p] * v[p];
      float vv = s * rdiag[r];
      v[r] = vv;
      sa += vv * vv;
    }
    contrib = sa;
  } else if (tid < 64) {
    float bq[32];
    float sb = 0.f;
#pragma unroll
    for (int r = 0; r < 32; ++r) {
      float s = m_u[d * 32 + r];
#pragma unroll
      for (int p = 0; p < 32; ++p)
        if (p < r) s -= Kl[r * 33 + p] * bq[p];
      float vv = s * __builtin_amdgcn_rcpf(Kl[r * 33 + r]);
      bq[r] = vv;
      sb += vv * vv;
    }
    contrib = (tid == 32) ? sb : 0.f;
  }
  if (tid < 64) red[tid] = contrib;
  __syncthreads();
  if (tid == 0) {
    float s = 0.f;
    for (int i = 0; i < 64; ++i) s += red[i];
    float ldK = 0.f, ldS = 0.f;
    for (int r = 0; r < 32; ++r) {
      ldK += logf(Kl[r * 33 + r]);
      ldS += logf(fabsf(L_u[(d * 32 + r) * 32 + r]) + 1e-12f);
    }
    float g = s - 32.0f + 2.0f * ldK - 2.0f * ldS;
    atomicAdd(&acc[1], 0.5f * g / (128.0f * 256.0f));
  }
}

// ---- Fused prep kernel (772 blocks) ----------------------------------------
__global__ __launch_bounds__(256) void prep_kernel(
    const float* obs,
    const float* W1, const float* b1, const float* W2, const float* b2,
    const float* W3, const float* b3, const float* W4, const float* b4,
    const float* Wih, const float* Whh, const float* b_lstm,
    const float* Wm, const float* bm, const float* Wv, const float* bv,
    const float* Z, const float* log_ls, const float* log_os,
    const float* m_u, const float* L_u,
    uint32_t kUa, uint32_t kUb,
    float* par_g, float* m0_g, float* v0_g,
    float* Krot_g, float* alpha_g, float* acc) {
  __shared__ __align__(16) float smem[12480];
  const int bx = blockIdx.x;
  if (bx < 512) {
    mlp_part(smem, obs, W1, b1, W2, b2, W3, b3, W4, b4, par_g);
  } else if (bx < 768) {
    lstm_part(smem, bx - 512, obs, Wih, Whh, b_lstm, Wm, bm, Wv, bv, m0_g, v0_g, acc);
  } else {
    setup_part(smem, bx - 768, Z, log_ls, log_os, m_u, L_u, kUa, kUb,
               Krot_g, alpha_g, acc);
  }
}

// ===========================================================================
// Scan: 4096 chains; 32 lanes/chain; 2 chains per wave; packed-f32 math.
// Quadratic form via symmetric fold: qp = sum_m k_m * sum_j Krot[m][j]*k_{(m+j)&31}
// (17 rotated terms/lane instead of 32, b64 LDS reads instead of b128).
// ===========================================================================
__global__ __launch_bounds__(256)
__attribute__((amdgpu_waves_per_eu(1, 2)))
void scan_kernel(
    const float* __restrict__ Z, const float* __restrict__ log_ls,
    const float* __restrict__ log_os, const float* __restrict__ noise_proc,
    const float* __restrict__ noise_emis, const float* __restrict__ obs,
    const float* __restrict__ par_g, const float* __restrict__ m0_g,
    const float* __restrict__ v0_g,
    const float* __restrict__ Krot_g, const float* __restrict__ alpha_g,
    uint32_t k0a, uint32_t k0b, uint32_t kqa, uint32_t kqb,
    float* __restrict__ acc, float* __restrict__ out) {
  __shared__ __align__(16) float parl_raw[32 * 36];
  __shared__ __align__(16) float parl_pk[32 * 40];   // packed per-step records
  __shared__ __align__(16) float obsl[32 * 4];
  __shared__ __align__(16) float eps0l[8 * 4 * 4];
  __shared__ __align__(16) v2f kbufv[8][2][32];      // [chain][dimpair][m]
  __shared__ __align__(16) float epsl[128 * 8 * 4];  // [t][c][s], 16 KB
  const int tid = threadIdx.x;
  const int c = tid >> 5;           // chain in block (0..7); own chain
  const int m = tid & 31;
  const int h = c & 1;              // dim-pair this lane owns (0:{0,1} 1:{2,3})
  const int cp = c & ~1;            // wave's chain pair base
  const int b = blockIdx.x >> 1;
  const int nb = (blockIdx.x & 1) << 3;
  const bool hh = (h != 0);

  // --- prologue RNG ---
#pragma unroll
  for (int i = 0; i < 8; ++i) {
    int e = tid + 256 * i;
    int t = e >> 5, cc = (e >> 2) & 7, ss = e & 3;
    uint32_t j = (uint32_t)(((t * 16 + nb + cc) * 256 + b) * 4 + ss);
    uint32_t o0, o1;
    threefry2x32(kqa, kqb, j, j + 1048576u, &o0, &o1);
    epsl[e] = bits_to_normal(o0);
    epsl[((t + 64) * 8 + cc) * 4 + ss] = bits_to_normal(o1);
  }
  if (tid < 128) {
    int cc = tid >> 4, dd = (tid >> 2) & 3, ss = tid & 3;
    uint32_t j = (uint32_t)((((cc * 4 + dd) * 256 + b) * 4) + ss);
    uint32_t o0, o1;
    threefry2x32(k0a, k0b, j, j + 32768u, &o0, &o1);
    eps0l[(cc * 4 + dd) * 4 + ss] = bits_to_normal(nb ? o1 : o0);
  }

  // --- per-lane constants (dim pair 2h, 2h+1) ---
  v2f ilp[4], nzp[4], osp;
#pragma unroll
  for (int k = 0; k < 4; ++k) {
    float i0 = expf(-log_ls[(2 * h + 0) * 4 + k]);
    float i1 = expf(-log_ls[(2 * h + 1) * 4 + k]);
    ilp[k] = v2(i0, i1);
    nzp[k] = v2(-Z[(2 * h + 0) * 128 + m * 4 + k] * i0,
                -Z[(2 * h + 1) * 128 + m * 4 + k] * i1);
  }
  osp = v2(expf(log_os[2 * h + 0]), expf(log_os[2 * h + 1]));

  v2f krot2[17];
  {
    const v2f* kg2 = (const v2f*)Krot_g;
#pragma unroll
    for (int j = 0; j < 17; ++j) krot2[j] = kg2[(h * 32 + m) * 17 + j];
  }
  int roff[17];
#pragma unroll
  for (int j = 0; j < 17; ++j) roff[j] = (m + j) & 31;

  v2f alrp[2];
#pragma unroll
  for (int cc = 0; cc < 2; ++cc)
    alrp[cc] = v2(alpha_g[((2 * h + 0) * 16 + nb + cp + cc) * 32 + m],
                  alpha_g[((2 * h + 1) * 16 + nb + cp + cc) * 32 + m]);
  float np_[4];
#pragma unroll
  for (int k = 0; k < 4; ++k) np_[k] = noise_proc[k];
  const float ine0 = __builtin_amdgcn_rcpf(noise_emis[0]);
  const float ine1 = __builtin_amdgcn_rcpf(noise_emis[1]);
  const float ine2 = __builtin_amdgcn_rcpf(noise_emis[2]);
  const float cst = 3.0f * LOG2PI_F + logf(noise_emis[0]) + logf(noise_emis[1]) + logf(noise_emis[2]);

  const float4 m0v = *(const float4*)(m0_g + b * 4);
  const float4 v0v = *(const float4*)(v0_g + b * 4);
  const float sq0 = sqrtf(v0v.x), sq1 = sqrtf(v0v.y), sq2 = sqrtf(v0v.z), sq3 = sqrtf(v0v.w);

  // --- peeled t=0 RBF (eps0-based; needs cross-wave eps0l -> barrier) ---
  __syncthreads();
  v2f kt0[2];
#pragma unroll
  for (int cc = 0; cc < 2; ++cc) {
    const float4 ea = *(const float4*)&eps0l[((cp + cc) * 4 + 2 * h + 0) * 4];
    const float4 eb = *(const float4*)&eps0l[((cp + cc) * 4 + 2 * h + 1) * 4];
    v2f xt0p = v2(fmaf(sq0, ea.x, m0v.x), fmaf(sq0, eb.x, m0v.x));
    v2f xt1p = v2(fmaf(sq1, ea.y, m0v.y), fmaf(sq1, eb.y, m0v.y));
    v2f xt2p = v2(fmaf(sq2, ea.z, m0v.z), fmaf(sq2, eb.z, m0v.z));
    v2f xt3p = v2(fmaf(sq3, ea.w, m0v.w), fmaf(sq3, eb.w, m0v.w));
    v2f d0 = PKFMA(xt0p, ilp[0], nzp[0]);
    v2f d1 = PKFMA(xt1p, ilp[1], nzp[1]);
    v2f d2 = PKFMA(xt2p, ilp[2], nzp[2]);
    v2f d3 = PKFMA(xt3p, ilp[3], nzp[3]);
    v2f ss = PKFMA(d0, d0, PKFMA(d1, d1, PKFMA(d2, d2, d3 * d3)));
    v2f km = osp * v2(__expf(-0.5f * ss.x), __expf(-0.5f * ss.y));
    kt0[cc] = km;
    kbufv[cp + cc][h][m] = km;
  }

  float x0r = 0.f, x1r = 0.f, x2r = 0.f, x3r = 0.f;  // own chain's x
  float kl_acc = 0.f, ell_acc = 0.f;

  for (int tc = 0; tc < 4; ++tc) {
    __syncthreads();
    {  // stage raw par chunk + obs chunk
      const float4* src = (const float4*)(par_g + (size_t)b * 4608 + tc * 1152);
      float4* dst = (float4*)parl_raw;
      for (int i = tid; i < 288; i += 256) dst[i] = src[i];
      if (tid < 96) obsl[(tid / 3) * 4 + (tid % 3)] = obs[b * 384 + tc * 96 + tid];
    }
    __syncthreads();
    {  // transform to packed layout: 8 workers per step
      int st = tid >> 3, w = tid & 7;
      const float* r = parl_raw + st * 36;
      float* o = parl_pk + st * 40;
      if (w < 4) {              // A column pairs (k = w)
        o[2 * w + 0] = r[0 * 4 + w]; o[2 * w + 1] = r[1 * 4 + w];
        o[8 + 2 * w + 0] = r[2 * 4 + w]; o[8 + 2 * w + 1] = r[3 * 4 + w];
      } else if (w == 4) {      // bt
        o[16] = r[16]; o[17] = r[17]; o[18] = r[18]; o[19] = r[19];
      } else if (w == 5) {      // St col0
        float l00 = r[20];
        o[20] = l00 * l00;
        o[21] = r[24] * l00;
        o[22] = r[28] * l00;
        o[23] = r[32] * l00;
      } else if (w == 6) {      // {St21,St31}, St11
        o[24] = r[28] * r[24] + r[29] * r[25];
        o[25] = r[32] * r[24] + r[33] * r[25];
        o[28] = r[24] * r[24] + r[25] * r[25];
      } else {                  // {St22,St32}, St33
        o[26] = r[28] * r[28] + r[29] * r[29] + r[30] * r[30];
        o[27] = r[32] * r[28] + r[33] * r[29] + r[34] * r[30];
        o[29] = r[32] * r[32] + r[33] * r[33] + r[34] * r[34] + r[35] * r[35];
      }
    }
    __syncthreads();

#pragma unroll 1
    for (int tt = 0; tt < 32; ++tt) {
      const int t = tc * 32 + tt;
      const v2f* pk = (const v2f*)&parl_pk[tt * 40];
      v2f Ac01[4], Ac23[4];
#pragma unroll
      for (int k = 0; k < 4; ++k) { Ac01[k] = pk[k]; Ac23[k] = pk[4 + k]; }
      const v2f bt01 = pk[8], bt23 = pk[9];
      const v2f StA = pk[10];   // {St00,St10}
      const v2f StB = pk[11];   // {St20,St30}
      const v2f StD = pk[12];   // {St21,St31}
      const v2f StE = pk[13];   // {St22,St32}
      const v2f Stx = pk[14];   // {St11,St33}
      const float4 ov = *(const float4*)&obsl[tt * 4];
      const float4 ev = *(const float4*)&epsl[(t * 8 + c) * 4];

      // phase 1: RBF features (dim pair packed) x 2 chains
      v2f kregp[2];
      if (t != 0) {
        const float xo0 = __shfl_xor(x0r, 32);
        const float xo1 = __shfl_xor(x1r, 32);
        const float xo2 = __shfl_xor(x2r, 32);
        const float xo3 = __shfl_xor(x3r, 32);
#pragma unroll
        for (int cc = 0; cc < 2; ++cc) {
          const bool own = (cc == h);
          float xt0 = own ? x0r : xo0;
          float xt1 = own ? x1r : xo1;
          float xt2 = own ? x2r : xo2;
          float xt3 = own ? x3r : xo3;
          v2f d0 = PKFMA(v2s(xt0), ilp[0], nzp[0]);
          v2f d1 = PKFMA(v2s(xt1), ilp[1], nzp[1]);
          v2f d2 = PKFMA(v2s(xt2), ilp[2], nzp[2]);
          v2f d3 = PKFMA(v2s(xt3), ilp[3], nzp[3]);
          v2f ss = PKFMA(d0, d0, PKFMA(d1, d1, PKFMA(d2, d2, d3 * d3)));
          v2f km = osp * v2(__expf(-0.5f * ss.x), __expf(-0.5f * ss.y));
          kregp[cc] = km;
          kbufv[cp + cc][h][m] = km;   // wave-internal write
        }
      } else {
        kregp[0] = kt0[0];
        kregp[1] = kt0[1];             // kbuf already holds t0 values
      }

      // phase 2: symmetric-fold quadratic form + reductions, both chains
      v2f gmloc[2], gvloc[2];
#pragma unroll
      for (int cc = 0; cc < 2; ++cc) {
        const v2f* kb = &kbufv[cp + cc][h][0];
        v2f aq0 = krot2[0] * kregp[cc];
        v2f aq1 = v2s(0.f);
#pragma unroll
        for (int j = 1; j <= 16; j += 2) {
          aq0 = PKFMA(krot2[j], kb[roff[j]], aq0);
          if (j + 1 <= 16) aq1 = PKFMA(krot2[j + 1], kb[roff[j + 1]], aq1);
        }
        v2f qpp = kregp[cc] * (aq0 + aq1);
        v2f gmp = kregp[cc] * alrp[cc];
        gmloc[cc] = v2(allred32(gmp.x), allred32(gmp.y));
        v2f qpr = v2(allred32(qpp.x), allred32(qpp.y));
        gvloc[cc] = __builtin_elementwise_max(osp - qpr, v2s(1e-8f));
      }

      // cross-half exchange (R7-proven)
      v2f sgm = hh ? gmloc[0] : gmloc[1];
      v2f sgv = hh ? gvloc[0] : gvloc[1];
      v2f rgm = v2(__shfl_xor(sgm.x, 32), __shfl_xor(sgm.y, 32));
      v2f rgv = v2(__shfl_xor(sgv.x, 32), __shfl_xor(sgv.y, 32));
      v2f lgm = hh ? gmloc[1] : gmloc[0];
      v2f lgv = hh ? gvloc[1] : gvloc[0];
      v2f gm01 = hh ? rgm : lgm;
      v2f gm23 = hh ? lgm : rgm;
      v2f gv01 = hh ? rgv : lgv;
      v2f gv23 = hh ? lgv : rgv;
      const float gm0 = gm01.x, gm1 = gm01.y, gm2 = gm23.x, gm3 = gm23.y;
      const float gv0 = gv01.x, gv1 = gv01.y, gv2 = gv23.x, gv3 = gv23.y;

      // q_mean (row pairs)
      v2f qm01 = bt01, qm23 = bt23;
      qm01 = PKFMA(Ac01[0], v2s(gm0), qm01);
      qm01 = PKFMA(Ac01[1], v2s(gm1), qm01);
      qm01 = PKFMA(Ac01[2], v2s(gm2), qm01);
      qm01 = PKFMA(Ac01[3], v2s(gm3), qm01);
      qm23 = PKFMA(Ac23[0], v2s(gm0), qm23);
      qm23 = PKFMA(Ac23[1], v2s(gm1), qm23);
      qm23 = PKFMA(Ac23[2], v2s(gm2), qm23);
      qm23 = PKFMA(Ac23[3], v2s(gm3), qm23);

      // B = A * diag(gv), row pairs
      v2f B01[4], B23[4];
      B01[0] = Ac01[0] * v2s(gv0); B23[0] = Ac23[0] * v2s(gv0);
      B01[1] = Ac01[1] * v2s(gv1); B23[1] = Ac23[1] * v2s(gv1);
      B01[2] = Ac01[2] * v2s(gv2); B23[2] = Ac23[2] * v2s(gv2);
      B01[3] = Ac01[3] * v2s(gv3); B23[3] = Ac23[3] * v2s(gv3);

      // q_cov = St + B A^T (lower triangle, packed)
      v2f c0a = StA, c0b = StB, c1 = StD, c2 = StE;
      float c11 = Stx.x, c33 = Stx.y;
#pragma unroll
      for (int k = 0; k < 4; ++k) {
        float A0k = Ac01[k].x, A1k = Ac01[k].y, A2k = Ac23[k].x, A3k = Ac23[k].y;
        c0a = PKFMA(B01[k], v2s(A0k), c0a);   // {qc00, qc10}
        c0b = PKFMA(B23[k], v2s(A0k), c0b);   // {qc20, qc30}
        c1  = PKFMA(B23[k], v2s(A1k), c1);    // {qc21, qc31}
        c2  = PKFMA(B23[k], v2s(A2k), c2);    // {qc22, qc32}
        c11 = fmaf(B01[k].y, A1k, c11);
        c33 = fmaf(B23[k].y, A3k, c33);
      }
      const float qc00 = c0a.x, qc10 = c0a.y, qc20 = c0b.x, qc30 = c0b.y;
      const float qc11 = c11, qc21 = c1.x, qc31 = c1.y;
      const float qc22 = c2.x, qc32 = c2.y, qc33 = c33;

      // Cholesky via rsq
      float t00 = qc00 + 1e-6f;
      float i0 = __builtin_amdgcn_rsqf(t00);
      float l00 = t00 * i0;
      float l10 = qc10 * i0, l20 = qc20 * i0, l30 = qc30 * i0;
      float t11 = qc11 + 1e-6f - l10 * l10;
      float i1 = __builtin_amdgcn_rsqf(t11);
      float l11 = t11 * i1;
      float l21 = (qc21 - l20 * l10) * i1;
      float l31 = (qc31 - l30 * l10) * i1;
      float t22 = qc22 + 1e-6f - l20 * l20 - l21 * l21;
      float i2 = __builtin_amdgcn_rsqf(t22);
      float l22 = t22 * i2;
      float l32 = (qc32 - l30 * l20 - l31 * l21) * i2;
      float t33 = qc33 + 1e-6f - l30 * l30 - l31 * l31 - l32 * l32;
      float l33 = t33 * __builtin_amdgcn_rsqf(t33);
      float logdet_q = __logf(t00 * t11 * t22 * t33);

      float dp0 = gv0 + np_[0], dp1 = gv1 + np_[1];
      float dp2 = gv2 + np_[2], dp3 = gv3 + np_[3];
      float rp0 = __builtin_amdgcn_rcpf(dp0), rp1 = __builtin_amdgcn_rcpf(dp1);
      float rp2 = __builtin_amdgcn_rcpf(dp2), rp3 = __builtin_amdgcn_rcpf(dp3);
      v2f e01 = gm01 - qm01, e23 = gm23 - qm23;
      float klsum = (qc00 + e01.x * e01.x) * rp0 + (qc11 + e01.y * e01.y) * rp1 +
                    (qc22 + e23.x * e23.x) * rp2 + (qc33 + e23.y * e23.y) * rp3;
      float kl = 0.5f * (klsum - 4.0f + __logf(dp0 * dp1 * dp2 * dp3) - logdet_q);
      kl_acc += kl;

      float dy0 = ov.x - qm01.x, dy1 = ov.y - qm01.y, dy2 = ov.z - qm23.x;
      float es = -0.5f * (cst + (dy0 * dy0 + qc00) * ine0 +
                          (dy1 * dy1 + qc11) * ine1 + (dy2 * dy2 + qc22) * ine2);
      ell_acc += es;

      x0r = qm01.x + l00 * ev.x;
      x1r = qm01.y + l10 * ev.x + l11 * ev.y;
      x2r = qm23.x + l20 * ev.x + l21 * ev.y + l22 * ev.z;
      x3r = qm23.y + l30 * ev.x + l31 * ev.y + l32 * ev.z + l33 * ev.w;
    }
  }

  if (m == 0) {
    atomicAdd(&acc[2], kl_acc);
    atomicAdd(&acc[3], ell_acc);
  }
  __syncthreads();
  // fused finalize: last block to finish computes the ELBO
  if (tid == 0) {
    __threadfence();
    unsigned prev = atomicAdd((unsigned int*)&acc[8], 1u);
    if (prev == 511u) {
      __threadfence();
      float qm0 = atomicAdd(&acc[0], 0.0f) / 256.0f;
      float gpKL = atomicAdd(&acc[1], 0.0f);
      float KL = atomicAdd(&acc[2], 0.0f) / 4096.0f;
      float lik = atomicAdd(&acc[3], 0.0f) / 4096.0f;
      float e = -qm0 - gpKL + lik - KL;
      if (lik > KL) e = -qm0 - gpKL + lik / 128.0f - KL;
      out[0] = e;
    }
  }
}

// ---------------------------------------------------------------------------
extern "C" void kernel_launch(void* const* d_in, const int* in_sizes, int n_in,
                              void* d_out, int out_size, void* d_ws, size_t ws_size,
                              hipStream_t stream) {
  const float* obs        = (const float*)d_in[0];
  const float* Z          = (const float*)d_in[1];
  const float* log_ls     = (const float*)d_in[2];
  const float* log_os     = (const float*)d_in[3];
  const float* m_u        = (const float*)d_in[4];
  const float* L_u        = (const float*)d_in[5];
  const float* noise_proc = (const float*)d_in[6];
  const float* noise_emis = (const float*)d_in[7];
  const float* Wih        = (const float*)d_in[8];
  const float* Whh        = (const float*)d_in[9];
  const float* b_lstm     = (const float*)d_in[10];
  const float* Wm         = (const float*)d_in[11];
  const float* bm         = (const float*)d_in[12];
  const float* Wv         = (const float*)d_in[13];
  const float* bv         = (const float*)d_in[14];
  const float* W1         = (const float*)d_in[15];
  const float* b1         = (const float*)d_in[16];
  const float* W2         = (const float*)d_in[17];
  const float* b2         = (const float*)d_in[18];
  const float* W3         = (const float*)d_in[19];
  const float* b3         = (const float*)d_in[20];
  const float* W4         = (const float*)d_in[21];
  const float* b4         = (const float*)d_in[22];

  float* ws = (float*)d_ws;
  float* m0_g  = ws;                 // 1024
  float* v0_g  = m0_g + 1024;        // 1024
  float* par_g = v0_g + 1024;        // 1179648
  float* krotg = par_g + 1179648;    // 2176 used (4096 reserved)
  float* alphg = krotg + 4096;       // 2048
  float* accp  = alphg + 2048;       // 16 (acc[8] doubles as completion cnt)

  hipMemsetAsync(accp, 0, 64, stream);

  // JAX: rng = key(42) -> (0,42); k0,kU,kq = split(rng,3)
  uint32_t A0, B0, A1, B1, A2, B2;
  threefry2x32(0u, 42u, 0u, 3u, &A0, &B0);
  threefry2x32(0u, 42u, 1u, 4u, &A1, &B1);
  threefry2x32(0u, 42u, 2u, 5u, &A2, &B2);
  const uint32_t k0a = A0, k0b = A1;   // k0
  const uint32_t kUa = A2, kUb = B0;   // kU
  const uint32_t kqa = B1, kqb = B2;   // kq

  // prep: mlp [0,512) + lstm [512,768) + setup [768,772)
  prep_kernel<<<772, 256, 0, stream>>>(
      obs, W1, b1, W2, b2, W3, b3, W4, b4,
      Wih, Whh, b_lstm, Wm, bm, Wv, bv,
      Z, log_ls, log_os, m_u, L_u,
      kUa, kUb,
      par_g, m0_g, v0_g, krotg, alphg, accp);

  scan_kernel<<<512, 256, 0, stream>>>(
      Z, log_ls, log_os, noise_proc, noise_emis, obs,
      par_g, m0_g, v0_g, krotg, alphg, k0a, k0b, kqa, kqb, accp,
      (float*)d_out);
}

// Round 11
// 534.943 us; speedup vs baseline: 1.0329x; 1.0005x over previous
//
#include <hip/hip_runtime.h>
#include <cstdint>
#include <math.h>

// Problem constants
#define NMC   16
#define SDIM  4
#define ODIM  3
#define TLEN  128
#define BDIM  256
#define MDIM  32
#define HLDIM 64
#define PARD  36

#define LOG2PI_F 1.8378770664093453f

typedef float v2f __attribute__((ext_vector_type(2)));
__device__ __forceinline__ v2f v2(float x, float y) { v2f r; r.x = x; r.y = y; return r; }
__device__ __forceinline__ v2f v2s(float x) { return v2(x, x); }
#define PKFMA(a, b, c) __builtin_elementwise_fma((a), (b), (c))

// ---------------------------------------------------------------------------
// threefry2x32 (JAX-compatible, 20 rounds)
// ---------------------------------------------------------------------------
__host__ __device__ inline void threefry2x32(uint32_t k0, uint32_t k1,
                                             uint32_t x0, uint32_t x1,
                                             uint32_t* o0, uint32_t* o1) {
  uint32_t ks0 = k0, ks1 = k1, ks2 = k0 ^ k1 ^ 0x1BD11BDAu;
  x0 += ks0; x1 += ks1;
#define TF_R(r) { x0 += x1; x1 = (x1 << (r)) | (x1 >> (32 - (r))); x1 ^= x0; }
  TF_R(13) TF_R(15) TF_R(26) TF_R(6)  x0 += ks1; x1 += ks2 + 1u;
  TF_R(17) TF_R(29) TF_R(16) TF_R(24) x0 += ks2; x1 += ks0 + 2u;
  TF_R(13) TF_R(15) TF_R(26) TF_R(6)  x0 += ks0; x1 += ks1 + 3u;
  TF_R(17) TF_R(29) TF_R(16) TF_R(24) x0 += ks1; x1 += ks2 + 4u;
  TF_R(13) TF_R(15) TF_R(26) TF_R(6)  x0 += ks2; x1 += ks0 + 5u;
#undef TF_R
  *o0 = x0; *o1 = x1;
}

// XLA f32 ErfInv polynomial
__device__ inline float erfinv_f32(float x) {
  float w = -log1pf(-x * x);
  float p;
  if (w < 5.0f) {
    w -= 2.5f;
    p = 2.81022636e-08f;
    p = fmaf(p, w, 3.43273939e-07f);
    p = fmaf(p, w, -3.5233877e-06f);
    p = fmaf(p, w, -4.39150654e-06f);
    p = fmaf(p, w, 0.00021858087f);
    p = fmaf(p, w, -0.00125372503f);
    p = fmaf(p, w, -0.00417768164f);
    p = fmaf(p, w, 0.246640727f);
    p = fmaf(p, w, 1.50140941f);
  } else {
    w = sqrtf(w) - 3.0f;
    p = -0.000200214257f;
    p = fmaf(p, w, 0.000100950558f);
    p = fmaf(p, w, 0.00134934322f);
    p = fmaf(p, w, -0.00367342844f);
    p = fmaf(p, w, 0.00573950773f);
    p = fmaf(p, w, -0.0076224613f);
    p = fmaf(p, w, 0.00943887047f);
    p = fmaf(p, w, 1.00167406f);
    p = fmaf(p, w, 2.83297682f);
  }
  return p * x;
}

__device__ inline float bits_to_normal(uint32_t b) {
  float f = __uint_as_float((b >> 9) | 0x3F800000u) - 1.0f;  // [0,1)
  const float lo = -0.99999994f;
  float u = f * 2.0f + lo;
  u = fmaxf(lo, u);
  return 1.41421356f * erfinv_f32(u);
}

// ---------------------------------------------------------------------------
// DPP-based allreduce within each 32-lane group (R7-proven form)
// ---------------------------------------------------------------------------
#define DPP_ROR_ADD(v, ctrl) \
  ((v) + __int_as_float(__builtin_amdgcn_update_dpp(0, __float_as_int(v), (ctrl), 0xf, 0xf, false)))

__device__ __forceinline__ float allred32(float v) {
  v = DPP_ROR_ADD(v, 0x128);  // row_ror:8
  v = DPP_ROR_ADD(v, 0x124);  // row_ror:4
  v = DPP_ROR_ADD(v, 0x122);  // row_ror:2
  v = DPP_ROR_ADD(v, 0x121);  // row_ror:1
  return v + __shfl_xor(v, 16);
}

__device__ __forceinline__ float sigm_fast(float x) {
  return 1.0f / (1.0f + __expf(-x));
}
__device__ __forceinline__ float tanh_fast(float x) {
  return 1.0f - 2.0f / (1.0f + __expf(2.0f * x));
}

// ===========================================================================
// PREP parts (fused kernel; 256 threads; shared smem arena 12480 floats)
// ===========================================================================

// ---- MLP part: blocks [0,512), 64 rows/block -------------------------------
#define MLP_SB 128
__device__ void mlp_part(
    float* smem, const float* __restrict__ obs,
    const float* __restrict__ W1, const float* __restrict__ b1,
    const float* __restrict__ W2, const float* __restrict__ b2,
    const float* __restrict__ W3, const float* __restrict__ b3,
    const float* __restrict__ W4, const float* __restrict__ b4,
    float* __restrict__ par_g) {
  float* xs  = smem;           // [3][64]
  float* A_l = smem + 192;     // 64*64
  float* B_l = smem + 192 + 4096;  // 64*128
  const int tid = threadIdx.x;
  const int R0 = blockIdx.x * 64;
  const int tr = tid & 15;
  const int tj = tid >> 4;

  for (int idx = tid; idx < 192; idx += 256) {
    int r = idx & 63, o = idx >> 6;
    xs[o * 64 + r] = obs[(R0 + r) * 3 + o];
  }

  float acc2[4][8];
#pragma unroll
  for (int i = 0; i < 4; ++i)
#pragma unroll
    for (int j = 0; j < 8; ++j) acc2[i][j] = 0.f;

  for (int kc = 0; kc < 4; ++kc) {
    __syncthreads();
    {  // stage W2 chunk transposed
      int j = tid & 127, kh = (tid >> 7) * 32;
      const float4* wsrc = (const float4*)(W2 + j * 256 + kc * 64 + kh);
#pragma unroll
      for (int q = 0; q < 8; ++q) {
        float4 v = wsrc[q];
        int k = kh + q * 4;
        B_l[(k + 0) * MLP_SB + j] = v.x;
        B_l[(k + 1) * MLP_SB + j] = v.y;
        B_l[(k + 2) * MLP_SB + j] = v.z;
        B_l[(k + 3) * MLP_SB + j] = v.w;
      }
    }
    {  // layer1 on the fly
      int r = tid & 63, q4 = tid >> 6;
      float x0 = xs[r], x1 = xs[64 + r], x2 = xs[128 + r];
      const float4* w1p = (const float4*)(W1 + (kc * 64 + q4 * 16) * 3);
      float4 wv[12];
#pragma unroll
      for (int q = 0; q < 12; ++q) wv[q] = w1p[q];
      const float* wf = (const float*)wv;
#pragma unroll
      for (int i = 0; i < 16; ++i) {
        int k = q4 * 16 + i;
        float v = b1[kc * 64 + k] + wf[i * 3] * x0 + wf[i * 3 + 1] * x1 + wf[i * 3 + 2] * x2;
        A_l[k * 64 + r] = fmaxf(v, 0.f);
      }
    }
    __syncthreads();
    for (int k = 0; k < 64; ++k) {
      float4 av = *(const float4*)&A_l[k * 64 + tr * 4];
      float4 b0 = *(const float4*)&B_l[k * MLP_SB + tj * 8];
      float4 b1v = *(const float4*)&B_l[k * MLP_SB + tj * 8 + 4];
      const float a4[4] = {av.x, av.y, av.z, av.w};
      const float bv8[8] = {b0.x, b0.y, b0.z, b0.w, b1v.x, b1v.y, b1v.z, b1v.w};
#pragma unroll
      for (int ri = 0; ri < 4; ++ri)
#pragma unroll
        for (int ji = 0; ji < 8; ++ji)
          acc2[ri][ji] = fmaf(a4[ri], bv8[ji], acc2[ri][ji]);
    }
  }
  __syncthreads();
#pragma unroll
  for (int ji = 0; ji < 8; ++ji) {
    int j = tj * 8 + ji;
    float bias = b2[j];
    float4 hv;
    hv.x = fmaxf(acc2[0][ji] + bias, 0.f);
    hv.y = fmaxf(acc2[1][ji] + bias, 0.f);
    hv.z = fmaxf(acc2[2][ji] + bias, 0.f);
    hv.w = fmaxf(acc2[3][ji] + bias, 0.f);
    *(float4*)&B_l[j * 64 + tr * 4] = hv;
  }

  float acc3[4][4];
#pragma unroll
  for (int i = 0; i < 4; ++i)
#pragma unroll
    for (int j = 0; j < 4; ++j) acc3[i][j] = 0.f;

  for (int kc = 0; kc < 2; ++kc) {
    __syncthreads();
    {
      int j = tid & 63, kq = (tid >> 6) * 16;
      const float4* wsrc = (const float4*)(W3 + j * 128 + kc * 64 + kq);
#pragma unroll
      for (int q = 0; q < 4; ++q) {
        float4 v = wsrc[q];
        int k = kq + q * 4;
        A_l[(k + 0) * 64 + j] = v.x;
        A_l[(k + 1) * 64 + j] = v.y;
        A_l[(k + 2) * 64 + j] = v.z;
        A_l[(k + 3) * 64 + j] = v.w;
      }
    }
    __syncthreads();
    for (int k = 0; k < 64; ++k) {
      float4 av = *(const float4*)&B_l[(kc * 64 + k) * 64 + tr * 4];
      float4 bv = *(const float4*)&A_l[k * 64 + (tj & 15) * 4];
      const float a4[4] = {av.x, av.y, av.z, av.w};
      const float b4v[4] = {bv.x, bv.y, bv.z, bv.w};
#pragma unroll
      for (int ri = 0; ri < 4; ++ri)
#pragma unroll
        for (int ji = 0; ji < 4; ++ji)
          acc3[ri][ji] = fmaf(a4[ri], b4v[ji], acc3[ri][ji]);
    }
  }
  __syncthreads();
#pragma unroll
  for (int ji = 0; ji < 4; ++ji) {
    int j = tj * 4 + ji;
    float bias = b3[j];
    float4 hv;
    hv.x = fmaxf(acc3[0][ji] + bias, 0.f);
    hv.y = fmaxf(acc3[1][ji] + bias, 0.f);
    hv.z = fmaxf(acc3[2][ji] + bias, 0.f);
    hv.w = fmaxf(acc3[3][ji] + bias, 0.f);
    *(float4*)&A_l[j * 64 + tr * 4] = hv;
  }
  __syncthreads();

  {
    int r = tid & 63;
    int jg = __builtin_amdgcn_readfirstlane(tid >> 6);
    float accp[9];
#pragma unroll
    for (int i = 0; i < 9; ++i) accp[i] = b4[jg * 9 + i];
    for (int k = 0; k < 64; ++k) {
      float hv = A_l[k * 64 + r];
#pragma unroll
      for (int i = 0; i < 9; ++i)
        accp[i] = fmaf(hv, W4[(jg * 9 + i) * 64 + k], accp[i]);
    }
#pragma unroll
    for (int i = 0; i < 9; ++i) par_g[(R0 + r) * 36 + jg * 9 + i] = accp[i];
  }
}

// ---- LSTM part: blocks [512,768) -------------------------------------------
__device__ void lstm_part(
    float* smem, int b, const float* __restrict__ obs,
    const float* __restrict__ Wih, const float* __restrict__ Whh,
    const float* __restrict__ b_lstm,
    const float* __restrict__ Wm, const float* __restrict__ bm,
    const float* __restrict__ Wv, const float* __restrict__ bv,
    float* __restrict__ m0_g, float* __restrict__ v0_g, float* __restrict__ acc) {
  float* g_l = smem;          // [2][4][64]
  float* h_w = smem + 512;    // [4][64]
  float* mv_l = smem + 768;   // 8
  float* obl = smem + 776;    // [128][4] padded
  const int tid = threadIdx.x;
  const int w = tid >> 6;
  const int l = tid & 63;

  for (int i = tid; i < 384; i += 256) obl[(i / 3) * 4 + (i % 3)] = obs[b * 384 + i];

  float whh_r[64];
  {
    const float4* wsrc = (const float4*)(Whh + tid * 64);
#pragma unroll
    for (int q = 0; q < 16; ++q) {
      float4 v = wsrc[q];
      whh_r[q * 4 + 0] = v.x; whh_r[q * 4 + 1] = v.y;
      whh_r[q * 4 + 2] = v.z; whh_r[q * 4 + 3] = v.w;
    }
  }
  const float wih0 = Wih[tid * 3 + 0];
  const float wih1 = Wih[tid * 3 + 1];
  const float wih2 = Wih[tid * 3 + 2];
  const float bb = b_lstm[tid];

  float c_ = 0.0f;
  h_w[w * 64 + l] = 0.0f;
  __syncthreads();

#pragma unroll 1
  for (int t = 0; t < TLEN; ++t) {
    const float4 xv = *(const float4*)&obl[t * 4];
    const float4* h4 = (const float4*)&h_w[w * 64];
    float a0 = 0.f, a1 = 0.f, a2 = 0.f, a3 = 0.f;
#pragma unroll
    for (int q = 0; q < 16; ++q) {
      float4 hv = h4[q];
      a0 = fmaf(whh_r[q * 4 + 0], hv.x, a0);
      a1 = fmaf(whh_r[q * 4 + 1], hv.y, a1);
      a2 = fmaf(whh_r[q * 4 + 2], hv.z, a2);
      a3 = fmaf(whh_r[q * 4 + 3], hv.w, a3);
    }
    float g = fmaf(wih0, xv.x, fmaf(wih1, xv.y, fmaf(wih2, xv.z, bb))) + ((a0 + a1) + (a2 + a3));
    g_l[((t & 1) * 4 + w) * 64 + l] = g;
    __syncthreads();
    float gi = g_l[((t & 1) * 4 + 0) * 64 + l];
    float gf = g_l[((t & 1) * 4 + 1) * 64 + l];
    float gg = g_l[((t & 1) * 4 + 2) * 64 + l];
    float go = g_l[((t & 1) * 4 + 3) * 64 + l];
    c_ = sigm_fast(gf) * c_ + sigm_fast(gi) * tanh_fast(gg);
    h_w[w * 64 + l] = sigm_fast(go) * tanh_fast(c_);
  }

  if (tid < 8) {
    const int s = tid & 3;
    const bool isv = tid >= 4;
    const float* W = isv ? (Wv + s * 64) : (Wm + s * 64);
    float a = isv ? bv[s] : bm[s];
#pragma unroll
    for (int k = 0; k < 64; ++k) a += W[k] * h_w[k];
    if (!isv) {
      m0_g[b * 4 + s] = a;
      mv_l[s] = a;
    } else {
      float sp = (a > 0.f) ? (a + log1pf(expf(-a))) : log1pf(expf(a));
      float v = sp + 1e-6f;
      v0_g[b * 4 + s] = v;
      mv_l[4 + s] = v;
    }
  }
  if (tid == 0) {
    float s = 0.f;
#pragma unroll
    for (int k = 0; k < 4; ++k) {
      float m = mv_l[k], v = mv_l[4 + k];
      s += 0.5f * (v + m * m - 1.0f - logf(v));
    }
    atomicAdd(&acc[0], s);
  }
}

// ---- SETUP part: blocks [768,772), per-d -----------------------------------
// Writes ROTATED pre-scaled symmetric-fold kernel matrix:
//   Krot_g[(p*32+m)*34 + j*2 + comp], d = 2p+comp, j in [0,17):
//     j==0 : Kinv[m][m];  j in 1..15 : 2*Kinv[m][(m+j)&31];  j==16 : Kinv[m][(m+16)&31]
__device__ void setup_part(
    float* smem, int d, const float* __restrict__ Z,
    const float* __restrict__ log_ls, const float* __restrict__ log_os,
    const float* __restrict__ m_u, const float* __restrict__ L_u,
    uint32_t kUa, uint32_t kUb,
    float* __restrict__ Krot_g, float* __restrict__ alpha_g, float* __restrict__ acc) {
  float* Kl    = smem;          // 32*33
  float* work  = smem + 1056;   // 32*33
  float* Ul    = smem + 2112;   // 16*32
  float* red   = smem + 2624;   // 64
  float* epsUl = smem + 2688;   // 16*32
  const int tid = threadIdx.x;

  {
    int nn7 = tid >> 5, k = tid & 31;
    uint32_t j = (uint32_t)((nn7 * 4 + d) * 32 + k);
    uint32_t o0, o1;
    threefry2x32(kUa, kUb, j, j + 1024u, &o0, &o1);
    epsUl[nn7 * 32 + k] = bits_to_normal(o0);
    epsUl[(nn7 + 8) * 32 + k] = bits_to_normal(o1);
  }

  float il[4];
#pragma unroll
  for (int k = 0; k < 4; ++k) il[k] = expf(-log_ls[d * 4 + k]);
  const float osd = expf(log_os[d]);

  for (int e = tid; e < 1024; e += 256) {
    int i = e >> 5, j = e & 31;
    float s = 0.f;
#pragma unroll
    for (int k = 0; k < 4; ++k) {
      float t_ = (Z[d * 128 + i * 4 + k] - Z[d * 128 + j * 4 + k]) * il[k];
      s += t_ * t_;
    }
    float v = osd * expf(-0.5f * s);
    if (i == j) v += 1e-5f;
    Kl[i * 33 + j] = v;
  }
  __syncthreads();

  for (int jc = 0; jc < 32; ++jc) {
    if (tid == jc) {
      float s = Kl[jc * 33 + jc];
      for (int p = 0; p < jc; ++p) s -= Kl[jc * 33 + p] * Kl[jc * 33 + p];
      Kl[jc * 33 + jc] = sqrtf(s);
    }
    __syncthreads();
    if (tid > jc && tid < 32) {
      float s = Kl[tid * 33 + jc];
      for (int p = 0; p < jc; ++p) s -= Kl[tid * 33 + p] * Kl[jc * 33 + p];
      Kl[tid * 33 + jc] = s / Kl[jc * 33 + jc];
    }
    __syncthreads();
  }

  if (tid < 32) {
    const int col = tid;
    float rdiag[32];
#pragma unroll
    for (int r = 0; r < 32; ++r) rdiag[r] = __builtin_amdgcn_rcpf(Kl[r * 33 + r]);
    float w[32];
#pragma unroll
    for (int r = 0; r < 32; ++r) {
      float s = (r == col) ? 1.f : 0.f;
#pragma unroll
      for (int p = 0; p < 32; ++p)
        if (p < r) s -= Kl[r * 33 + p] * w[p];
      w[r] = s * rdiag[r];
    }
    float w2[32];
#pragma unroll
    for (int rr = 0; rr < 32; ++rr) {
      const int r = 31 - rr;
      float s = w[r];
#pragma unroll
      for (int p = 0; p < 32; ++p)
        if (p > r) s -= Kl[p * 33 + r] * w2[p];
      w2[r] = s * rdiag[r];
    }
#pragma unroll
    for (int r = 0; r < 32; ++r) work[col * 33 + r] = w2[r];
  }
  for (int e = tid; e < 512; e += 256) {
    int nn = e >> 5, m = e & 31;
    float s = m_u[d * 32 + m];
    for (int k = 0; k <= m; ++k)
      s += L_u[(d * 32 + m) * 32 + k] * epsUl[nn * 32 + k];
    Ul[nn * 32 + m] = s;
  }
  __syncthreads();
  for (int e = tid; e < 512; e += 256) {
    int nn = e >> 5, m = e & 31;
    float s = 0.f;
    for (int mm = 0; mm < 32; ++mm) s += work[mm * 33 + m] * Ul[nn * 32 + mm];
    alpha_g[(d * 16 + nn) * 32 + m] = s;
  }
  __syncthreads();  // work reads (alpha) done before krot extraction below

  // Rotated pre-scaled Krot for the symmetric quadratic-form fold.
  // Kinv[m][col] = work[col*33 + m] (Kinv symmetric).
  for (int e = tid; e < 32 * 17; e += 256) {
    int mm = e / 17, j = e - mm * 17;
    int col = (mm + j) & 31;
    float scale = (j == 0 || j == 16) ? 1.0f : 2.0f;
    Krot_g[((d >> 1) * 32 + mm) * 34 + j * 2 + (d & 1)] = scale * work[col * 33 + mm];
  }
  __syncthreads();  // krot reads done before gpKL overwrites work

  float contrib = 0.f;
  if (tid < 32) {
    const int col = tid;
    float rdiag[32];
#pragma unroll
    for (int r = 0; r < 32; ++r) rdiag[r] = __builtin_amdgcn_rcpf(Kl[r * 33 + r]);
    float v[32];
    float sa = 0.f;
#pragma unroll
    for (int r = 0; r < 32; ++r) {
      float lu = L_u[(d * 32 + r) * 32 + col];
      float s = (col <= r) ? lu : 0.f;
#pragma unroll
      for (int p = 0; p < 32; ++p)
        if (p < r) s -= Kl[r * 33 + p] * v[p];
      float vv = s * rdiag[r];
      v[r] = vv;
      sa += vv * vv;
    }
    contrib = sa;
  } else if (tid < 64) {
    float bq[32];
    float sb = 0.f;
#pragma unroll
    for (int r = 0; r < 32; ++r) {
      float s = m_u[d * 32 + r];
#pragma unroll
      for (int p = 0; p < 32; ++p)
        if (p < r) s -= Kl[r * 33 + p] * bq[p];
      float vv = s * __builtin_amdgcn_rcpf(Kl[r * 33 + r]);
      bq[r] = vv;
      sb += vv * vv;
    }
    contrib = (tid == 32) ? sb : 0.f;
  }
  if (tid < 64) red[tid] = contrib;
  __syncthreads();
  if (tid == 0) {
    float s = 0.f;
    for (int i = 0; i < 64; ++i) s += red[i];
    float ldK = 0.f, ldS = 0.f;
    for (int r = 0; r < 32; ++r) {
      ldK += logf(Kl[r * 33 + r]);
      ldS += logf(fabsf(L_u[(d * 32 + r) * 32 + r]) + 1e-12f);
    }
    float g = s - 32.0f + 2.0f * ldK - 2.0f * ldS;
    atomicAdd(&acc[1], 0.5f * g / (128.0f * 256.0f));
  }
}

// ---- Fused prep kernel (772 blocks) ----------------------------------------
__global__ __launch_bounds__(256) void prep_kernel(
    const float* obs,
    const float* W1, const float* b1, const float* W2, const float* b2,
    const float* W3, const float* b3, const float* W4, const float* b4,
    const float* Wih, const float* Whh, const float* b_lstm,
    const float* Wm, const float* bm, const float* Wv, const float* bv,
    const float* Z, const float* log_ls, const float* log_os,
    const float* m_u, const float* L_u,
    uint32_t kUa, uint32_t kUb,
    float* par_g, float* m0_g, float* v0_g,
    float* Krot_g, float* alpha_g, float* acc) {
  __shared__ __align__(16) float smem[12480];
  const int bx = blockIdx.x;
  if (bx < 512) {
    mlp_part(smem, obs, W1, b1, W2, b2, W3, b3, W4, b4, par_g);
  } else if (bx < 768) {
    lstm_part(smem, bx - 512, obs, Wih, Whh, b_lstm, Wm, bm, Wv, bv, m0_g, v0_g, acc);
  } else {
    setup_part(smem, bx - 768, Z, log_ls, log_os, m_u, L_u, kUa, kUb,
               Krot_g, alpha_g, acc);
  }
}

// ===========================================================================
// Scan: 4096 chains; 32 lanes/chain; 2 chains per wave; packed-f32 math.
// Quadratic form via symmetric fold with MIRRORED kbuf ring (64 entries):
// window reads kb[m+1..m+16] are linear constant offsets -> ds_read2_b64.
// ===========================================================================
__global__ __launch_bounds__(256)
__attribute__((amdgpu_waves_per_eu(1, 2)))
void scan_kernel(
    const float* __restrict__ Z, const float* __restrict__ log_ls,
    const float* __restrict__ log_os, const float* __restrict__ noise_proc,
    const float* __restrict__ noise_emis, const float* __restrict__ obs,
    const float* __restrict__ par_g, const float* __restrict__ m0_g,
    const float* __restrict__ v0_g,
    const float* __restrict__ Krot_g, const float* __restrict__ alpha_g,
    uint32_t k0a, uint32_t k0b, uint32_t kqa, uint32_t kqb,
    float* __restrict__ acc, float* __restrict__ out) {
  __shared__ __align__(16) float parl_raw[32 * 36];
  __shared__ __align__(16) float parl_pk[32 * 40];   // packed per-step records
  __shared__ __align__(16) float obsl[32 * 4];
  __shared__ __align__(16) float eps0l[8 * 4 * 4];
  __shared__ __align__(16) v2f kbufv[8][2][64];      // [chain][dimpair][m] MIRRORED
  __shared__ __align__(16) float epsl[128 * 8 * 4];  // [t][c][s], 16 KB
  const int tid = threadIdx.x;
  const int c = tid >> 5;           // chain in block (0..7); own chain
  const int m = tid & 31;
  const int h = c & 1;              // dim-pair this lane owns (0:{0,1} 1:{2,3})
  const int cp = c & ~1;            // wave's chain pair base
  const int b = blockIdx.x >> 1;
  const int nb = (blockIdx.x & 1) << 3;
  const bool hh = (h != 0);

  // --- prologue RNG ---
#pragma unroll
  for (int i = 0; i < 8; ++i) {
    int e = tid + 256 * i;
    int t = e >> 5, cc = (e >> 2) & 7, ss = e & 3;
    uint32_t j = (uint32_t)(((t * 16 + nb + cc) * 256 + b) * 4 + ss);
    uint32_t o0, o1;
    threefry2x32(kqa, kqb, j, j + 1048576u, &o0, &o1);
    epsl[e] = bits_to_normal(o0);
    epsl[((t + 64) * 8 + cc) * 4 + ss] = bits_to_normal(o1);
  }
  if (tid < 128) {
    int cc = tid >> 4, dd = (tid >> 2) & 3, ss = tid & 3;
    uint32_t j = (uint32_t)((((cc * 4 + dd) * 256 + b) * 4) + ss);
    uint32_t o0, o1;
    threefry2x32(k0a, k0b, j, j + 32768u, &o0, &o1);
    eps0l[(cc * 4 + dd) * 4 + ss] = bits_to_normal(nb ? o1 : o0);
  }

  // --- per-lane constants (dim pair 2h, 2h+1) ---
  v2f ilp[4], nzp[4], osp;
#pragma unroll
  for (int k = 0; k < 4; ++k) {
    float i0 = expf(-log_ls[(2 * h + 0) * 4 + k]);
    float i1 = expf(-log_ls[(2 * h + 1) * 4 + k]);
    ilp[k] = v2(i0, i1);
    nzp[k] = v2(-Z[(2 * h + 0) * 128 + m * 4 + k] * i0,
                -Z[(2 * h + 1) * 128 + m * 4 + k] * i1);
  }
  osp = v2(expf(log_os[2 * h + 0]), expf(log_os[2 * h + 1]));

  v2f krot2[17];
  {
    const v2f* kg2 = (const v2f*)Krot_g;
#pragma unroll
    for (int j = 0; j < 17; ++j) krot2[j] = kg2[(h * 32 + m) * 17 + j];
  }

  v2f alrp[2];
#pragma unroll
  for (int cc = 0; cc < 2; ++cc)
    alrp[cc] = v2(alpha_g[((2 * h + 0) * 16 + nb + cp + cc) * 32 + m],
                  alpha_g[((2 * h + 1) * 16 + nb + cp + cc) * 32 + m]);
  float np_[4];
#pragma unroll
  for (int k = 0; k < 4; ++k) np_[k] = noise_proc[k];
  const float ine0 = __builtin_amdgcn_rcpf(noise_emis[0]);
  const float ine1 = __builtin_amdgcn_rcpf(noise_emis[1]);
  const float ine2 = __builtin_amdgcn_rcpf(noise_emis[2]);
  const float cst = 3.0f * LOG2PI_F + logf(noise_emis[0]) + logf(noise_emis[1]) + logf(noise_emis[2]);

  const float4 m0v = *(const float4*)(m0_g + b * 4);
  const float4 v0v = *(const float4*)(v0_g + b * 4);
  const float sq0 = sqrtf(v0v.x), sq1 = sqrtf(v0v.y), sq2 = sqrtf(v0v.z), sq3 = sqrtf(v0v.w);

  // --- peeled t=0 RBF (eps0-based; needs cross-wave eps0l -> barrier) ---
  __syncthreads();
  v2f kt0[2];
#pragma unroll
  for (int cc = 0; cc < 2; ++cc) {
    const float4 ea = *(const float4*)&eps0l[((cp + cc) * 4 + 2 * h + 0) * 4];
    const float4 eb = *(const float4*)&eps0l[((cp + cc) * 4 + 2 * h + 1) * 4];
    v2f xt0p = v2(fmaf(sq0, ea.x, m0v.x), fmaf(sq0, eb.x, m0v.x));
    v2f xt1p = v2(fmaf(sq1, ea.y, m0v.y), fmaf(sq1, eb.y, m0v.y));
    v2f xt2p = v2(fmaf(sq2, ea.z, m0v.z), fmaf(sq2, eb.z, m0v.z));
    v2f xt3p = v2(fmaf(sq3, ea.w, m0v.w), fmaf(sq3, eb.w, m0v.w));
    v2f d0 = PKFMA(xt0p, ilp[0], nzp[0]);
    v2f d1 = PKFMA(xt1p, ilp[1], nzp[1]);
    v2f d2 = PKFMA(xt2p, ilp[2], nzp[2]);
    v2f d3 = PKFMA(xt3p, ilp[3], nzp[3]);
    v2f ss = PKFMA(d0, d0, PKFMA(d1, d1, PKFMA(d2, d2, d3 * d3)));
    v2f km = osp * v2(__expf(-0.5f * ss.x), __expf(-0.5f * ss.y));
    kt0[cc] = km;
    kbufv[cp + cc][h][m] = km;
    kbufv[cp + cc][h][m + 32] = km;
  }

  float x0r = 0.f, x1r = 0.f, x2r = 0.f, x3r = 0.f;  // own chain's x
  float kl_acc = 0.f, ell_acc = 0.f;

  for (int tc = 0; tc < 4; ++tc) {
    __syncthreads();
    {  // stage raw par chunk + obs chunk
      const float4* src = (const float4*)(par_g + (size_t)b * 4608 + tc * 1152);
      float4* dst = (float4*)parl_raw;
      for (int i = tid; i < 288; i += 256) dst[i] = src[i];
      if (tid < 96) obsl[(tid / 3) * 4 + (tid % 3)] = obs[b * 384 + tc * 96 + tid];
    }
    __syncthreads();
    {  // transform to packed layout: 8 workers per step
      int st = tid >> 3, w = tid & 7;
      const float* r = parl_raw + st * 36;
      float* o = parl_pk + st * 40;
      if (w < 4) {              // A column pairs (k = w)
        o[2 * w + 0] = r[0 * 4 + w]; o[2 * w + 1] = r[1 * 4 + w];
        o[8 + 2 * w + 0] = r[2 * 4 + w]; o[8 + 2 * w + 1] = r[3 * 4 + w];
      } else if (w == 4) {      // bt
        o[16] = r[16]; o[17] = r[17]; o[18] = r[18]; o[19] = r[19];
      } else if (w == 5) {      // St col0
        float l00 = r[20];
        o[20] = l00 * l00;
        o[21] = r[24] * l00;
        o[22] = r[28] * l00;
        o[23] = r[32] * l00;
      } else if (w == 6) {      // {St21,St31}, St11
        o[24] = r[28] * r[24] + r[29] * r[25];
        o[25] = r[32] * r[24] + r[33] * r[25];
        o[28] = r[24] * r[24] + r[25] * r[25];
      } else {                  // {St22,St32}, St33
        o[26] = r[28] * r[28] + r[29] * r[29] + r[30] * r[30];
        o[27] = r[32] * r[28] + r[33] * r[29] + r[34] * r[30];
        o[29] = r[32] * r[32] + r[33] * r[33] + r[34] * r[34] + r[35] * r[35];
      }
    }
    __syncthreads();

#pragma unroll 1
    for (int tt = 0; tt < 32; ++tt) {
      const int t = tc * 32 + tt;
      const v2f* pk = (const v2f*)&parl_pk[tt * 40];
      v2f Ac01[4], Ac23[4];
#pragma unroll
      for (int k = 0; k < 4; ++k) { Ac01[k] = pk[k]; Ac23[k] = pk[4 + k]; }
      const v2f bt01 = pk[8], bt23 = pk[9];
      const v2f StA = pk[10];   // {St00,St10}
      const v2f StB = pk[11];   // {St20,St30}
      const v2f StD = pk[12];   // {St21,St31}
      const v2f StE = pk[13];   // {St22,St32}
      const v2f Stx = pk[14];   // {St11,St33}
      const float4 ov = *(const float4*)&obsl[tt * 4];
      const float4 ev = *(const float4*)&epsl[(t * 8 + c) * 4];

      // phase 1: RBF features (dim pair packed) x 2 chains
      v2f kregp[2];
      if (t != 0) {
        const float xo0 = __shfl_xor(x0r, 32);
        const float xo1 = __shfl_xor(x1r, 32);
        const float xo2 = __shfl_xor(x2r, 32);
        const float xo3 = __shfl_xor(x3r, 32);
#pragma unroll
        for (int cc = 0; cc < 2; ++cc) {
          const bool own = (cc == h);
          float xt0 = own ? x0r : xo0;
          float xt1 = own ? x1r : xo1;
          float xt2 = own ? x2r : xo2;
          float xt3 = own ? x3r : xo3;
          v2f d0 = PKFMA(v2s(xt0), ilp[0], nzp[0]);
          v2f d1 = PKFMA(v2s(xt1), ilp[1], nzp[1]);
          v2f d2 = PKFMA(v2s(xt2), ilp[2], nzp[2]);
          v2f d3 = PKFMA(v2s(xt3), ilp[3], nzp[3]);
          v2f ss = PKFMA(d0, d0, PKFMA(d1, d1, PKFMA(d2, d2, d3 * d3)));
          v2f km = osp * v2(__expf(-0.5f * ss.x), __expf(-0.5f * ss.y));
          kregp[cc] = km;
          kbufv[cp + cc][h][m] = km;        // mirrored ring write
          kbufv[cp + cc][h][m + 32] = km;
        }
      } else {
        kregp[0] = kt0[0];
        kregp[1] = kt0[1];             // kbuf already holds t0 values
      }

      // phase 2: symmetric-fold quadratic form + reductions, both chains.
      // Mirrored ring: window [m+1, m+16] is linear -> constant offsets.
      v2f gmloc[2], gvloc[2];
#pragma unroll
      for (int cc = 0; cc < 2; ++cc) {
        const v2f* kb = &kbufv[cp + cc][h][m];   // lane-relative base
        v2f aq0 = krot2[0] * kregp[cc];
        v2f aq1 = v2s(0.f);
#pragma unroll
        for (int j = 1; j <= 16; j += 2) {
          aq0 = PKFMA(krot2[j], kb[j], aq0);
          if (j + 1 <= 16) aq1 = PKFMA(krot2[j + 1], kb[j + 1], aq1);
        }
        v2f qpp = kregp[cc] * (aq0 + aq1);
        v2f gmp = kregp[cc] * alrp[cc];
        gmloc[cc] = v2(allred32(gmp.x), allred32(gmp.y));
        v2f qpr = v2(allred32(qpp.x), allred32(qpp.y));
        gvloc[cc] = __builtin_elementwise_max(osp - qpr, v2s(1e-8f));
      }

      // cross-half exchange (R7-proven)
      v2f sgm = hh ? gmloc[0] : gmloc[1];
      v2f sgv = hh ? gvloc[0] : gvloc[1];
      v2f rgm = v2(__shfl_xor(sgm.x, 32), __shfl_xor(sgm.y, 32));
      v2f rgv = v2(__shfl_xor(sgv.x, 32), __shfl_xor(sgv.y, 32));
      v2f lgm = hh ? gmloc[1] : gmloc[0];
      v2f lgv = hh ? gvloc[1] : gvloc[0];
      v2f gm01 = hh ? rgm : lgm;
      v2f gm23 = hh ? lgm : rgm;
      v2f gv01 = hh ? rgv : lgv;
      v2f gv23 = hh ? lgv : rgv;
      const float gm0 = gm01.x, gm1 = gm01.y, gm2 = gm23.x, gm3 = gm23.y;
      const float gv0 = gv01.x, gv1 = gv01.y, gv2 = gv23.x, gv3 = gv23.y;

      // q_mean (row pairs)
      v2f qm01 = bt01, qm23 = bt23;
      qm01 = PKFMA(Ac01[0], v2s(gm0), qm01);
      qm01 = PKFMA(Ac01[1], v2s(gm1), qm01);
      qm01 = PKFMA(Ac01[2], v2s(gm2), qm01);
      qm01 = PKFMA(Ac01[3], v2s(gm3), qm01);
      qm23 = PKFMA(Ac23[0], v2s(gm0), qm23);
      qm23 = PKFMA(Ac23[1], v2s(gm1), qm23);
      qm23 = PKFMA(Ac23[2], v2s(gm2), qm23);
      qm23 = PKFMA(Ac23[3], v2s(gm3), qm23);

      // B = A * diag(gv), row pairs
      v2f B01[4], B23[4];
      B01[0] = Ac01[0] * v2s(gv0); B23[0] = Ac23[0] * v2s(gv0);
      B01[1] = Ac01[1] * v2s(gv1); B23[1] = Ac23[1] * v2s(gv1);
      B01[2] = Ac01[2] * v2s(gv2); B23[2] = Ac23[2] * v2s(gv2);
      B01[3] = Ac01[3] * v2s(gv3); B23[3] = Ac23[3] * v2s(gv3);

      // q_cov = St + B A^T (lower triangle, packed)
      v2f c0a = StA, c0b = StB, c1 = StD, c2 = StE;
      float c11 = Stx.x, c33 = Stx.y;
#pragma unroll
      for (int k = 0; k < 4; ++k) {
        float A0k = Ac01[k].x, A1k = Ac01[k].y, A2k = Ac23[k].x, A3k = Ac23[k].y;
        c0a = PKFMA(B01[k], v2s(A0k), c0a);   // {qc00, qc10}
        c0b = PKFMA(B23[k], v2s(A0k), c0b);   // {qc20, qc30}
        c1  = PKFMA(B23[k], v2s(A1k), c1);    // {qc21, qc31}
        c2  = PKFMA(B23[k], v2s(A2k), c2);    // {qc22, qc32}
        c11 = fmaf(B01[k].y, A1k, c11);
        c33 = fmaf(B23[k].y, A3k, c33);
      }
      const float qc00 = c0a.x, qc10 = c0a.y, qc20 = c0b.x, qc30 = c0b.y;
      const float qc11 = c11, qc21 = c1.x, qc31 = c1.y;
      const float qc22 = c2.x, qc32 = c2.y, qc33 = c33;

      // Cholesky via rsq
      float t00 = qc00 + 1e-6f;
      float i0 = __builtin_amdgcn_rsqf(t00);
      float l00 = t00 * i0;
      float l10 = qc10 * i0, l20 = qc20 * i0, l30 = qc30 * i0;
      float t11 = qc11 + 1e-6f - l10 * l10;
      float i1 = __builtin_amdgcn_rsqf(t11);
      float l11 = t11 * i1;
      float l21 = (qc21 - l20 * l10) * i1;
      float l31 = (qc31 - l30 * l10) * i1;
      float t22 = qc22 + 1e-6f - l20 * l20 - l21 * l21;
      float i2 = __builtin_amdgcn_rsqf(t22);
      float l22 = t22 * i2;
      float l32 = (qc32 - l30 * l20 - l31 * l21) * i2;
      float t33 = qc33 + 1e-6f - l30 * l30 - l31 * l31 - l32 * l32;
      float l33 = t33 * __builtin_amdgcn_rsqf(t33);
      float logdet_q = __logf(t00 * t11 * t22 * t33);

      float dp0 = gv0 + np_[0], dp1 = gv1 + np_[1];
      float dp2 = gv2 + np_[2], dp3 = gv3 + np_[3];
      float rp0 = __builtin_amdgcn_rcpf(dp0), rp1 = __builtin_amdgcn_rcpf(dp1);
      float rp2 = __builtin_amdgcn_rcpf(dp2), rp3 = __builtin_amdgcn_rcpf(dp3);
      v2f e01 = gm01 - qm01, e23 = gm23 - qm23;
      float klsum = (qc00 + e01.x * e01.x) * rp0 + (qc11 + e01.y * e01.y) * rp1 +
                    (qc22 + e23.x * e23.x) * rp2 + (qc33 + e23.y * e23.y) * rp3;
      float kl = 0.5f * (klsum - 4.0f + __logf(dp0 * dp1 * dp2 * dp3) - logdet_q);
      kl_acc += kl;

      float dy0 = ov.x - qm01.x, dy1 = ov.y - qm01.y, dy2 = ov.z - qm23.x;
      float es = -0.5f * (cst + (dy0 * dy0 + qc00) * ine0 +
                          (dy1 * dy1 + qc11) * ine1 + (dy2 * dy2 + qc22) * ine2);
      ell_acc += es;

      x0r = qm01.x + l00 * ev.x;
      x1r = qm01.y + l10 * ev.x + l11 * ev.y;
      x2r = qm23.x + l20 * ev.x + l21 * ev.y + l22 * ev.z;
      x3r = qm23.y + l30 * ev.x + l31 * ev.y + l32 * ev.z + l33 * ev.w;
    }
  }

  if (m == 0) {
    atomicAdd(&acc[2], kl_acc);
    atomicAdd(&acc[3], ell_acc);
  }
  __syncthreads();
  // fused finalize: last block to finish computes the ELBO
  if (tid == 0) {
    __threadfence();
    unsigned prev = atomicAdd((unsigned int*)&acc[8], 1u);
    if (prev == 511u) {
      __threadfence();
      float qm0 = atomicAdd(&acc[0], 0.0f) / 256.0f;
      float gpKL = atomicAdd(&acc[1], 0.0f);
      float KL = atomicAdd(&acc[2], 0.0f) / 4096.0f;
      float lik = atomicAdd(&acc[3], 0.0f) / 4096.0f;
      float e = -qm0 - gpKL + lik - KL;
      if (lik > KL) e = -qm0 - gpKL + lik / 128.0f - KL;
      out[0] = e;
    }
  }
}

// ---------------------------------------------------------------------------
extern "C" void kernel_launch(void* const* d_in, const int* in_sizes, int n_in,
                              void* d_out, int out_size, void* d_ws, size_t ws_size,
                              hipStream_t stream) {
  const float* obs        = (const float*)d_in[0];
  const float* Z          = (const float*)d_in[1];
  const float* log_ls     = (const float*)d_in[2];
  const float* log_os     = (const float*)d_in[3];
  const float* m_u        = (const float*)d_in[4];
  const float* L_u        = (const float*)d_in[5];
  const float* noise_proc = (const float*)d_in[6];
  const float* noise_emis = (const float*)d_in[7];
  const float* Wih        = (const float*)d_in[8];
  const float* Whh        = (const float*)d_in[9];
  const float* b_lstm     = (const float*)d_in[10];
  const float* Wm         = (const float*)d_in[11];
  const float* bm         = (const float*)d_in[12];
  const float* Wv         = (const float*)d_in[13];
  const float* bv         = (const float*)d_in[14];
  const float* W1         = (const float*)d_in[15];
  const float* b1         = (const float*)d_in[16];
  const float* W2         = (const float*)d_in[17];
  const float* b2         = (const float*)d_in[18];
  const float* W3         = (const float*)d_in[19];
  const float* b3         = (const float*)d_in[20];
  const float* W4         = (const float*)d_in[21];
  const float* b4         = (const float*)d_in[22];

  float* ws = (float*)d_ws;
  float* m0_g  = ws;                 // 1024
  float* v0_g  = m0_g + 1024;        // 1024
  float* par_g = v0_g + 1024;        // 1179648
  float* krotg = par_g + 1179648;    // 2176 used (4096 reserved)
  float* alphg = krotg + 4096;       // 2048
  float* accp  = alphg + 2048;       // 16 (acc[8] doubles as completion cnt)

  hipMemsetAsync(accp, 0, 64, stream);

  // JAX: rng = key(42) -> (0,42); k0,kU,kq = split(rng,3)
  uint32_t A0, B0, A1, B1, A2, B2;
  threefry2x32(0u, 42u, 0u, 3u, &A0, &B0);
  threefry2x32(0u, 42u, 1u, 4u, &A1, &B1);
  threefry2x32(0u, 42u, 2u, 5u, &A2, &B2);
  const uint32_t k0a = A0, k0b = A1;   // k0
  const uint32_t kUa = A2, kUb = B0;   // kU
  const uint32_t kqa = B1, kqb = B2;   // kq

  // prep: mlp [0,512) + lstm [512,768) + setup [768,772)
  prep_kernel<<<772, 256, 0, stream>>>(
      obs, W1, b1, W2, b2, W3, b3, W4, b4,
      Wih, Whh, b_lstm, Wm, bm, Wv, bv,
      Z, log_ls, log_os, m_u, L_u,
      kUa, kUb,
      par_g, m0_g, v0_g, krotg, alphg, accp);

  scan_kernel<<<512, 256, 0, stream>>>(
      Z, log_ls, log_os, noise_proc, noise_emis, obs,
      par_g, m0_g, v0_g, krotg, alphg, k0a, k0b, kqa, kqb, accp,
      (float*)d_out);
}